// Round 2
// baseline (573.361 us; speedup 1.0000x reference)
//
#include <hip/hip_runtime.h>
#include <hip/hip_bf16.h>
#include <math.h>

#define TDIM 16384
#define DDIM 1024
#define CDIM 256
#define KDIM 8192
#define KSPLIT 8

typedef unsigned short u16;
typedef __attribute__((ext_vector_type(8))) short bf16x8;
typedef __attribute__((ext_vector_type(8))) unsigned short us8;
typedef __attribute__((ext_vector_type(4))) float floatx4;

// ---- workspace layout (float offsets) ----
static const size_t OFF_WINH  = 0;                                     // 256x1024 u16
static const size_t OFF_WINL  = OFF_WINH  + (size_t)CDIM * DDIM / 2;
static const size_t OFF_WOUTH = OFF_WINL  + (size_t)CDIM * DDIM / 2;   // 1024x256 u16
static const size_t OFF_WOUTL = OFF_WOUTH + (size_t)DDIM * CDIM / 2;
static const size_t OFF_CBH   = OFF_WOUTL + (size_t)DDIM * CDIM / 2;   // 8192x256 u16
static const size_t OFF_CBL   = OFF_CBH   + (size_t)KDIM * CDIM / 2;
static const size_t OFF_C2    = OFF_CBL   + (size_t)KDIM * CDIM / 2;   // 8192 f32
static const size_t OFF_ZTH   = OFF_C2    + (size_t)KDIM;              // 16384x1024 u16 [t][d]
static const size_t OFF_ZTL   = OFF_ZTH   + (size_t)TDIM * DDIM / 2;
static const size_t OFF_ZE    = OFF_ZTL   + (size_t)TDIM * DDIM / 2;   // 256x16384 f32
static const size_t OFF_PV    = OFF_ZE    + (size_t)CDIM * TDIM;       // 8x16384 f32
static const size_t OFF_PI    = OFF_PV    + (size_t)KSPLIT * TDIM;     // 8x16384 i32
static const size_t OFF_IDX   = OFF_PI    + (size_t)KSPLIT * TDIM;     // 16384 i32
// eth/etl [t][c] alias ZTH (zth/ztl dead after in_proj gemm);
// zqh/zql alias the same region again (eth/etl dead after dist_mfma).
static const size_t OFF_ETH   = OFF_ZTH;
static const size_t OFF_ETL   = OFF_ZTH + (size_t)TDIM * CDIM / 2;

static __device__ __forceinline__ u16 f2bf(float x) {
  __hip_bfloat16 h = __float2bfloat16(x);
  return *(u16*)&h;
}
static __device__ __forceinline__ float bf2f(u16 u) {
  __hip_bfloat16 h; *(u16*)&h = u;
  return __bfloat162float(h);
}

// async global->LDS 16B copy (wave-uniform LDS base + lane*16; our per-lane
// pointers satisfy that by construction).
static __device__ __forceinline__ void gload16(const u16* g, u16* l) {
  __builtin_amdgcn_global_load_lds(
      (__attribute__((address_space(1))) void*)g,
      (__attribute__((address_space(3))) void*)l, 16, 0, 0);
}

// ---------------------------------------------------------------------------
// Row-wise L2 normalize -> bf16 hi/lo split. Optional g, clip, c2.
// ---------------------------------------------------------------------------
__global__ __launch_bounds__(256) void rownorm_split(
    const float* __restrict__ v, const float* __restrict__ g,
    u16* __restrict__ hi, u16* __restrict__ lo, float* __restrict__ c2,
    int ncols, int clip) {
  __shared__ float red[256];
  int row = blockIdx.x;
  const float* vr = v + (size_t)row * ncols;
  float s = 0.f;
  for (int j = threadIdx.x; j < ncols; j += 256) { float x = vr[j]; s += x * x; }
  red[threadIdx.x] = s;
  __syncthreads();
  for (int off = 128; off > 0; off >>= 1) {
    if (threadIdx.x < off) red[threadIdx.x] += red[threadIdx.x + off];
    __syncthreads();
  }
  float norm = sqrtf(red[0]);
  if (clip) norm = fmaxf(norm, 1e-12f);
  float scale = (g ? g[row] : 1.0f) / norm;
  float s2 = 0.f;
  for (int j = threadIdx.x; j < ncols; j += 256) {
    float y = vr[j] * scale;
    u16 hh = f2bf(y);
    u16 ll = f2bf(y - bf2f(hh));
    hi[(size_t)row * ncols + j] = hh;
    lo[(size_t)row * ncols + j] = ll;
    s2 += y * y;
  }
  if (c2) {
    __syncthreads();
    red[threadIdx.x] = s2;
    __syncthreads();
    for (int off = 128; off > 0; off >>= 1) {
      if (threadIdx.x < off) red[threadIdx.x] += red[threadIdx.x + off];
      __syncthreads();
    }
    if (threadIdx.x == 0) c2[row] = red[0];
  }
}

// ---------------------------------------------------------------------------
// z [d][t] fp32 -> zth/ztl [t][d] bf16 hi/lo (LDS 64x64 tile transpose)
// ---------------------------------------------------------------------------
__global__ __launch_bounds__(256) void transpose_split_z(
    const float* __restrict__ z, u16* __restrict__ zth, u16* __restrict__ ztl) {
  __shared__ float tile[64][65];
  int t0 = blockIdx.x * 64, d0 = blockIdx.y * 64;
  int tl = threadIdx.x & 63, grp = threadIdx.x >> 6;
#pragma unroll
  for (int r = 0; r < 16; r++) {
    int d = grp * 16 + r;
    tile[d][tl] = z[(size_t)(d0 + d) * TDIM + t0 + tl];
  }
  __syncthreads();
#pragma unroll
  for (int r = 0; r < 16; r++) {
    int t = grp * 16 + r;
    float x = tile[tl][t];
    u16 h = f2bf(x);
    u16 l = f2bf(x - bf2f(h));
    zth[(size_t)(t0 + t) * DDIM + d0 + tl] = h;
    ztl[(size_t)(t0 + t) * DDIM + d0 + tl] = l;
  }
}

// ---------------------------------------------------------------------------
// in_proj split-bf16 MFMA GEMM, BN=64: C[m][t] = A[m]·B[t] + bias[m]
// ---------------------------------------------------------------------------
__global__ __launch_bounds__(256) void gemm_mfma_in(
    const u16* __restrict__ ah_g, const u16* __restrict__ al_g,
    const u16* __restrict__ bh_g, const u16* __restrict__ bl_g,
    const float* __restrict__ bias, float* __restrict__ C, int K) {
  __shared__ u16 Ah[128 * 32], Al[128 * 32];
  __shared__ u16 Bh[64 * 32],  Bl[64 * 32];
  int tid = threadIdx.x;
  int n0 = blockIdx.x * 64;      // t
  int m0 = blockIdx.y * 128;     // output rows
  int lane = tid & 63, wid = tid >> 6;
  int wr = wid >> 1, wc = wid & 1;
  int q = lane >> 4, mm = lane & 15;
  int h = tid & 1;
  int sr = ((tid >> 1) ^ (h << 2)) & 127;
  int ssw = (sr ^ (sr >> 2)) & 3;
  int o0 = sr * 32 + ((((h << 1))     ^ ssw) << 3);
  int o1 = sr * 32 + ((((h << 1) | 1) ^ ssw) << 3);
  int gcol = h * 16;
  // B staging (64 rows): threads tid<128 cover 64 rows x 2 halves
  int sb = ((tid >> 1) ^ (h << 2)) & 63;
  int ssb = (sb ^ (sb >> 2)) & 3;
  int p0 = sb * 32 + ((((h << 1))     ^ ssb) << 3);
  int p1 = sb * 32 + ((((h << 1) | 1) ^ ssb) << 3);
  int sm = (mm ^ (mm >> 2)) & 3;
  int cq = (q ^ sm) << 3;

  const floatx4 z4 = {0.f, 0.f, 0.f, 0.f};
  floatx4 acc[4][2];
#pragma unroll
  for (int i = 0; i < 4; i++)
#pragma unroll
    for (int j = 0; j < 2; j++) acc[i][j] = z4;

  for (int c0 = 0; c0 < K; c0 += 32) {
    const size_t ga = (size_t)(m0 + sr) * K + c0 + gcol;
    us8 a_h0 = *(const us8*)&ah_g[ga];
    us8 a_h1 = *(const us8*)&ah_g[ga + 8];
    us8 a_l0 = *(const us8*)&al_g[ga];
    us8 a_l1 = *(const us8*)&al_g[ga + 8];
    us8 b_h0, b_h1, b_l0, b_l1;
    if (tid < 128) {
      const size_t gb = (size_t)(n0 + sb) * K + c0 + gcol;
      b_h0 = *(const us8*)&bh_g[gb];
      b_h1 = *(const us8*)&bh_g[gb + 8];
      b_l0 = *(const us8*)&bl_g[gb];
      b_l1 = *(const us8*)&bl_g[gb + 8];
    }
    __syncthreads();
    *(us8*)&Ah[o0] = a_h0; *(us8*)&Ah[o1] = a_h1;
    *(us8*)&Al[o0] = a_l0; *(us8*)&Al[o1] = a_l1;
    if (tid < 128) {
      *(us8*)&Bh[p0] = b_h0; *(us8*)&Bh[p1] = b_h1;
      *(us8*)&Bl[p0] = b_l0; *(us8*)&Bl[p1] = b_l1;
    }
    __syncthreads();

    bf16x8 fa[4], fb[2];
#pragma unroll
    for (int i = 0; i < 4; i++)
      fa[i] = *(const bf16x8*)&Ah[(wr * 64 + i * 16 + mm) * 32 + cq];
#pragma unroll
    for (int j = 0; j < 2; j++)
      fb[j] = *(const bf16x8*)&Bh[(wc * 32 + j * 16 + mm) * 32 + cq];
#pragma unroll
    for (int i = 0; i < 4; i++)
#pragma unroll
      for (int j = 0; j < 2; j++)
        acc[i][j] = __builtin_amdgcn_mfma_f32_16x16x32_bf16(fa[i], fb[j], acc[i][j], 0, 0, 0);
#pragma unroll
    for (int i = 0; i < 4; i++) {
      bf16x8 fl = *(const bf16x8*)&Al[(wr * 64 + i * 16 + mm) * 32 + cq];
#pragma unroll
      for (int j = 0; j < 2; j++)
        acc[i][j] = __builtin_amdgcn_mfma_f32_16x16x32_bf16(fl, fb[j], acc[i][j], 0, 0, 0);
    }
#pragma unroll
    for (int j = 0; j < 2; j++) {
      bf16x8 fl = *(const bf16x8*)&Bl[(wc * 32 + j * 16 + mm) * 32 + cq];
#pragma unroll
      for (int i = 0; i < 4; i++)
        acc[i][j] = __builtin_amdgcn_mfma_f32_16x16x32_bf16(fa[i], fl, acc[i][j], 0, 0, 0);
    }
  }

#pragma unroll
  for (int i = 0; i < 4; i++) {
#pragma unroll
    for (int r = 0; r < 4; r++) {
      int m_loc = wr * 64 + i * 16 + q * 4 + r;
      float bb = bias[m0 + m_loc];
      float* crow = &C[(size_t)(m0 + m_loc) * TDIM + n0 + wc * 32 + mm];
#pragma unroll
      for (int j = 0; j < 2; j++) crow[j * 16] = acc[i][j][r] + bb;
    }
  }
}

// ---------------------------------------------------------------------------
// out_proj split-bf16 MFMA GEMM + bias, BN=128 (R6/R7-verified).
// ---------------------------------------------------------------------------
__global__ __launch_bounds__(256) void gemm_mfma_bias(
    const u16* __restrict__ ah_g, const u16* __restrict__ al_g,
    const u16* __restrict__ bh_g, const u16* __restrict__ bl_g,
    const float* __restrict__ bias, float* __restrict__ C, int K) {
  __shared__ u16 Ah[128 * 32], Al[128 * 32];
  __shared__ u16 Bh[128 * 32], Bl[128 * 32];
  int tid = threadIdx.x;
  int n0 = blockIdx.x * 128;
  int m0 = blockIdx.y * 128;
  int lane = tid & 63, wid = tid >> 6;
  int wr = wid >> 1, wc = wid & 1;
  int q = lane >> 4, mm = lane & 15;
  int h = tid & 1;
  int sr = ((tid >> 1) ^ (h << 2)) & 127;
  int ssw = (sr ^ (sr >> 2)) & 3;
  int o0 = sr * 32 + ((((h << 1))     ^ ssw) << 3);
  int o1 = sr * 32 + ((((h << 1) | 1) ^ ssw) << 3);
  int gcol = h * 16;
  int sm = (mm ^ (mm >> 2)) & 3;
  int cq = (q ^ sm) << 3;

  const floatx4 z4 = {0.f, 0.f, 0.f, 0.f};
  floatx4 acc[4][4];
#pragma unroll
  for (int i = 0; i < 4; i++)
#pragma unroll
    for (int j = 0; j < 4; j++) acc[i][j] = z4;

  for (int c0 = 0; c0 < K; c0 += 32) {
    const size_t ga = (size_t)(m0 + sr) * K + c0 + gcol;
    const size_t gb = (size_t)(n0 + sr) * K + c0 + gcol;
    us8 a_h0 = *(const us8*)&ah_g[ga];
    us8 a_h1 = *(const us8*)&ah_g[ga + 8];
    us8 a_l0 = *(const us8*)&al_g[ga];
    us8 a_l1 = *(const us8*)&al_g[ga + 8];
    us8 b_h0 = *(const us8*)&bh_g[gb];
    us8 b_h1 = *(const us8*)&bh_g[gb + 8];
    us8 b_l0 = *(const us8*)&bl_g[gb];
    us8 b_l1 = *(const us8*)&bl_g[gb + 8];
    __syncthreads();
    *(us8*)&Ah[o0] = a_h0; *(us8*)&Ah[o1] = a_h1;
    *(us8*)&Al[o0] = a_l0; *(us8*)&Al[o1] = a_l1;
    *(us8*)&Bh[o0] = b_h0; *(us8*)&Bh[o1] = b_h1;
    *(us8*)&Bl[o0] = b_l0; *(us8*)&Bl[o1] = b_l1;
    __syncthreads();

    bf16x8 fa[4], fb[4];
#pragma unroll
    for (int i = 0; i < 4; i++)
      fa[i] = *(const bf16x8*)&Ah[(wr * 64 + i * 16 + mm) * 32 + cq];
#pragma unroll
    for (int j = 0; j < 4; j++)
      fb[j] = *(const bf16x8*)&Bh[(wc * 64 + j * 16 + mm) * 32 + cq];
#pragma unroll
    for (int i = 0; i < 4; i++)
#pragma unroll
      for (int j = 0; j < 4; j++)
        acc[i][j] = __builtin_amdgcn_mfma_f32_16x16x32_bf16(fa[i], fb[j], acc[i][j], 0, 0, 0);
#pragma unroll
    for (int i = 0; i < 4; i++) {
      bf16x8 fl = *(const bf16x8*)&Al[(wr * 64 + i * 16 + mm) * 32 + cq];
#pragma unroll
      for (int j = 0; j < 4; j++)
        acc[i][j] = __builtin_amdgcn_mfma_f32_16x16x32_bf16(fl, fb[j], acc[i][j], 0, 0, 0);
    }
#pragma unroll
    for (int j = 0; j < 4; j++) {
      bf16x8 fl = *(const bf16x8*)&Bl[(wc * 64 + j * 16 + mm) * 32 + cq];
#pragma unroll
      for (int i = 0; i < 4; i++)
        acc[i][j] = __builtin_amdgcn_mfma_f32_16x16x32_bf16(fa[i], fl, acc[i][j], 0, 0, 0);
    }
  }

#pragma unroll
  for (int i = 0; i < 4; i++) {
#pragma unroll
    for (int r = 0; r < 4; r++) {
      int m_loc = wr * 64 + i * 16 + q * 4 + r;
      float bb = bias[m0 + m_loc];
      float* crow = &C[(size_t)(m0 + m_loc) * TDIM + n0 + wc * 64 + mm];
#pragma unroll
      for (int j = 0; j < 4; j++) crow[j * 16] = acc[i][j][r] + bb;
    }
  }
}

// ---------------------------------------------------------------------------
// finish_ze: fused column-norm + transpose + bf16 split, 32-t tiles.
// ---------------------------------------------------------------------------
__global__ __launch_bounds__(256) void finish_ze(
    const float* __restrict__ ze, u16* __restrict__ eth, u16* __restrict__ etl) {
  __shared__ float tile[256][33];
  __shared__ float red[8][32];
  __shared__ float invs[32];
  int t0 = blockIdx.x * 32;
  int tl = threadIdx.x & 31, grp = threadIdx.x >> 5;
  float s = 0.f;
  for (int c = grp * 32; c < grp * 32 + 32; c++) {
    float v = ze[(size_t)c * TDIM + t0 + tl];
    tile[c][tl] = v;
    s += v * v;
  }
  red[grp][tl] = s;
  __syncthreads();
  if (grp == 0) {
    float tot = 0.f;
#pragma unroll
    for (int gg = 0; gg < 8; gg++) tot += red[gg][tl];
    invs[tl] = 1.0f / fmaxf(sqrtf(tot), 1e-12f);
  }
  __syncthreads();
#pragma unroll
  for (int r = 0; r < 4; r++) {
    int t = grp * 4 + r;
    float iv = invs[t];
#pragma unroll
    for (int cc = 0; cc < 8; cc++) {
      int cd = cc * 32 + tl;
      float x = tile[cd][t] * iv;
      u16 hh = f2bf(x);
      u16 ll = f2bf(x - bf2f(hh));
      eth[(size_t)(t0 + t) * CDIM + cd] = hh;
      etl[(size_t)(t0 + t) * CDIM + cd] = ll;
    }
  }
}

// ---------------------------------------------------------------------------
// dist + argmin via split-bf16 MFMA — R9 RESTRUCTURE:
//   - B (enc) hi+lo loaded DIRECT global->reg per chunk (L1/L2-resident;
//     the wk-duplicated loads hit L1). Zero B LDS traffic.
//   - A (codebook) hi/lo staged via global_load_lds width-16 into BK=64,
//     128B-row-stride LDS with granule XOR swizzle (g ^= row&7), dbuf.
//     Inverse-swizzled SOURCE + linear LDS dest (gload_lds writes linearly).
//     Fragment reads conflict-free: slot = ((kk*4+q)^(mm&7)), 8 lanes/slot
//     = 1024B/128B hardware minimum.
//   - 16 chunks x 1 barrier (was 32 x 1); A-prefetch + B-loads issue before
//     the MFMA cluster -> latency hidden under ~3700cy MFMA per chunk.
// Per-(t,k) FMA sequence (c0 ascending by 32; per c0: hihi, lohi, hilo;
// fp32 MFMA accumulate) is IDENTICAL to the verified kernel -> dist values
// bit-equal -> indices bit-equal. Tie rules unchanged.
// LDS 132KB -> 1 block/CU, 8 waves (2/SIMD).
// ---------------------------------------------------------------------------
__global__ __launch_bounds__(512, 2) void dist_mfma(
    const u16* __restrict__ eth, const u16* __restrict__ etl,
    const u16* __restrict__ cbh, const u16* __restrict__ cbl,
    const float* __restrict__ c2, float* __restrict__ pv, int* __restrict__ pi) {
  __shared__ u16 AhL[2][256 * 64];   // 64 KB: codebook-hi dbuf, [row][64] swizzled
  __shared__ u16 AlL[2][256 * 64];   // 64 KB: codebook-lo dbuf
  __shared__ float mv[4][128];
  __shared__ int   mi[4][128];

  int tid = threadIdx.x;
  int t0 = blockIdx.x * 128;
  int kbeg = blockIdx.y * (KDIM / KSPLIT);
  int lane = tid & 63, wid = tid >> 6;
  int wk = wid >> 1, wt = wid & 1;       // 4 waves along k, 2 along t
  int q = lane >> 4, mm = lane & 15;

  // staging constants: thread covers granule gi = it*512+tid (it=0..3);
  // LDS linear pos gi holds global granule (gi&7)^(row&7) of the chunk.
  int stR[4], stC[4], stL[4];
#pragma unroll
  for (int it = 0; it < 4; it++) {
    int gi = it * 512 + tid;
    int r = gi >> 3, g = gi & 7;
    stR[it] = r;
    stC[it] = (g ^ (r & 7)) << 3;        // u16 col offset within 64-col chunk
    stL[it] = gi << 3;                   // u16 linear LDS offset
  }

  // A-fragment LDS read offsets (conflict-free swizzled), per kk
  int foff[2];
#pragma unroll
  for (int kk = 0; kk < 2; kk++)
    foff[kk] = ((((kk << 2) | q) ^ (mm & 7)) << 3);

  float rbv[4]; int rbi[4];
#pragma unroll
  for (int j = 0; j < 4; j++) { rbv[j] = INFINITY; rbi[j] = 0x7fffffff; }

  const floatx4 z4 = {0.f, 0.f, 0.f, 0.f};
  floatx4 acc[4][4];
#pragma unroll
  for (int i = 0; i < 4; i++)
#pragma unroll
    for (int j = 0; j < 4; j++) acc[i][j] = z4;

  // prologue: stage chunk 0 (k-step 0, c0=0) into buf 0
#pragma unroll
  for (int it = 0; it < 4; it++) {
    const size_t ga = (size_t)(kbeg + stR[it]) * CDIM + stC[it];
    gload16(&cbh[ga], &AhL[0][stL[it]]);
    gload16(&cbl[ga], &AlL[0][stL[it]]);
  }
  __syncthreads();

  for (int n = 0; n < 16; ++n) {         // 4 k-steps x 4 c0-chunks (BK=64)
    int b = n & 1;
    int c0 = (n & 3) * 64;

    // B direct loads for this chunk (global -> regs, L1/L2-hot)
    bf16x8 fbh[4][2], fbl[4][2];
#pragma unroll
    for (int j = 0; j < 4; j++) {
      const size_t gb = (size_t)(t0 + wt * 64 + j * 16 + mm) * CDIM + c0 + q * 8;
#pragma unroll
      for (int kk = 0; kk < 2; kk++) {
        fbh[j][kk] = *(const bf16x8*)&eth[gb + kk * 32];
        fbl[j][kk] = *(const bf16x8*)&etl[gb + kk * 32];
      }
    }

    // prefetch next A chunk into the other buffer (async, lands under MFMA)
    if (n < 15) {
      int n1 = n + 1;
      int k0n = kbeg + (n1 >> 2) * 256;
      int c0n = (n1 & 3) * 64;
#pragma unroll
      for (int it = 0; it < 4; it++) {
        const size_t ga = (size_t)(k0n + stR[it]) * CDIM + c0n + stC[it];
        gload16(&cbh[ga], &AhL[b ^ 1][stL[it]]);
        gload16(&cbl[ga], &AlL[b ^ 1][stL[it]]);
      }
    }

    // MFMA cluster: per 32-col slice (kk), terms hihi -> lohi -> hilo
#pragma unroll
    for (int kk = 0; kk < 2; kk++) {
      bf16x8 fah[4];
#pragma unroll
      for (int i = 0; i < 4; i++)
        fah[i] = *(const bf16x8*)&AhL[b][(wk * 64 + i * 16 + mm) * 64 + foff[kk]];
#pragma unroll
      for (int i = 0; i < 4; i++)
#pragma unroll
        for (int j = 0; j < 4; j++)
          acc[i][j] = __builtin_amdgcn_mfma_f32_16x16x32_bf16(fah[i], fbh[j][kk], acc[i][j], 0, 0, 0);
#pragma unroll
      for (int i = 0; i < 4; i++) {
        bf16x8 fl = *(const bf16x8*)&AlL[b][(wk * 64 + i * 16 + mm) * 64 + foff[kk]];
#pragma unroll
        for (int j = 0; j < 4; j++)
          acc[i][j] = __builtin_amdgcn_mfma_f32_16x16x32_bf16(fl, fbh[j][kk], acc[i][j], 0, 0, 0);
      }
#pragma unroll
      for (int j = 0; j < 4; j++) {
#pragma unroll
        for (int i = 0; i < 4; i++)
          acc[i][j] = __builtin_amdgcn_mfma_f32_16x16x32_bf16(fah[i], fbl[j][kk], acc[i][j], 0, 0, 0);
      }
    }

    // k-step epilogue: fold acc into running argmin, reset acc
    if ((n & 3) == 3) {
      int k0 = kbeg + (n >> 2) * 256;
#pragma unroll
      for (int i = 0; i < 4; i++) {
#pragma unroll
        for (int r4 = 0; r4 < 4; r4++) {
          int kg = k0 + wk * 64 + i * 16 + q * 4 + r4;
          float c2v = c2[kg];
#pragma unroll
          for (int j = 0; j < 4; j++) {
            float s = c2v - 2.0f * acc[i][j][r4];
            if (s < rbv[j]) { rbv[j] = s; rbi[j] = kg; }
          }
        }
      }
#pragma unroll
      for (int i = 0; i < 4; i++)
#pragma unroll
        for (int j = 0; j < 4; j++) acc[i][j] = z4;
    }

    __syncthreads();   // A-buf handoff (drains gload_lds + orders LDS reads)
  }

  // cross-lane reduce over q (lanes 16/32 apart hold same t)
#pragma unroll
  for (int j = 0; j < 4; j++) {
    float v = rbv[j]; int ii = rbi[j];
    float ov = __shfl_xor(v, 16, 64); int oi = __shfl_xor(ii, 16, 64);
    if (ov < v || (ov == v && oi < ii)) { v = ov; ii = oi; }
    ov = __shfl_xor(v, 32, 64); oi = __shfl_xor(ii, 32, 64);
    if (ov < v || (ov == v && oi < ii)) { v = ov; ii = oi; }
    rbv[j] = v; rbi[j] = ii;
  }
  if (q == 0) {
#pragma unroll
    for (int j = 0; j < 4; j++) {
      mv[wk][wt * 64 + j * 16 + mm] = rbv[j];
      mi[wk][wt * 64 + j * 16 + mm] = rbi[j];
    }
  }
  __syncthreads();
  if (tid < 128) {
    float v0 = mv[0][tid]; int i0 = mi[0][tid];
#pragma unroll
    for (int w = 1; w < 4; w++) {
      float v1 = mv[w][tid]; int i1 = mi[w][tid];
      if (v1 < v0 || (v1 == v0 && i1 < i0)) { v0 = v1; i0 = i1; }
    }
    pv[(size_t)blockIdx.y * TDIM + t0 + tid] = v0;
    pi[(size_t)blockIdx.y * TDIM + t0 + tid] = i0;
  }
}

// ---------------------------------------------------------------------------
// merge k-splits; emit int idx (for gather) and float idx (output 1)
// ---------------------------------------------------------------------------
__global__ __launch_bounds__(256) void merge_argmin(
    const float* __restrict__ pv, const int* __restrict__ pi,
    int* __restrict__ idx, float* __restrict__ idxf) {
  int t = blockIdx.x * 256 + threadIdx.x;
  float bv = INFINITY; int bi = 0x7fffffff;
  for (int s = 0; s < KSPLIT; s++) {
    float v = pv[(size_t)s * TDIM + t];
    int ii = pi[(size_t)s * TDIM + t];
    if (v < bv || (v == bv && ii < bi)) { bv = v; bi = ii; }
  }
  idx[t] = bi;
  idxf[t] = (float)bi;
}

// ---------------------------------------------------------------------------
// gather: zqT[t][c] = split(cb[idx[t]][c]); 4 t per block, float4 loads.
// ---------------------------------------------------------------------------
__global__ __launch_bounds__(256) void gather_split(
    const int* __restrict__ idx, const float* __restrict__ cb,
    u16* __restrict__ zqh, u16* __restrict__ zql) {
  int t = blockIdx.x * 4 + (threadIdx.x >> 6);
  int c4 = (threadIdx.x & 63) * 4;
  int k = idx[t];
  float4 x = *(const float4*)&cb[(size_t)k * CDIM + c4];
  u16 h0 = f2bf(x.x), h1 = f2bf(x.y), h2 = f2bf(x.z), h3 = f2bf(x.w);
  u16 l0 = f2bf(x.x - bf2f(h0)), l1 = f2bf(x.y - bf2f(h1));
  u16 l2 = f2bf(x.z - bf2f(h2)), l3 = f2bf(x.w - bf2f(h3));
  ushort4 hv = {h0, h1, h2, h3}, lv = {l0, l1, l2, l3};
  *(ushort4*)&zqh[(size_t)t * CDIM + c4] = hv;
  *(ushort4*)&zql[(size_t)t * CDIM + c4] = lv;
}

extern "C" void kernel_launch(void* const* d_in, const int* in_sizes, int n_in,
                              void* d_out, int out_size, void* d_ws, size_t ws_size,
                              hipStream_t stream) {
  const float* z     = (const float*)d_in[0];
  const float* in_v  = (const float*)d_in[1];
  const float* in_g  = (const float*)d_in[2];
  const float* in_b  = (const float*)d_in[3];
  const float* out_v = (const float*)d_in[4];
  const float* out_g = (const float*)d_in[5];
  const float* out_b = (const float*)d_in[6];
  const float* cb    = (const float*)d_in[7];

  float* ws    = (float*)d_ws;
  u16*   winh  = (u16*)(ws + OFF_WINH);
  u16*   winl  = (u16*)(ws + OFF_WINL);
  u16*   wouth = (u16*)(ws + OFF_WOUTH);
  u16*   woutl = (u16*)(ws + OFF_WOUTL);
  u16*   cbh   = (u16*)(ws + OFF_CBH);
  u16*   cbl   = (u16*)(ws + OFF_CBL);
  float* c2    = ws + OFF_C2;
  u16*   zth   = (u16*)(ws + OFF_ZTH);
  u16*   ztl   = (u16*)(ws + OFF_ZTL);
  float* z_e   = ws + OFF_ZE;
  float* pv    = ws + OFF_PV;
  int*   pi    = (int*)(ws + OFF_PI);
  int*   idxw  = (int*)(ws + OFF_IDX);
  u16*   eth   = (u16*)(ws + OFF_ETH);   // aliases zth (dead after in_proj)
  u16*   etl   = (u16*)(ws + OFF_ETL);
  u16*   zqh   = eth;                    // aliases eth (dead after dist)
  u16*   zql   = etl;

  float* outp = (float*)d_out;                 // (1024 x 16384) fp32
  float* idxf = outp + (size_t)DDIM * TDIM;    // indices as float32

  // weight prep: all weights emitted directly as split-bf16
  rownorm_split<<<CDIM, 256, 0, stream>>>(in_v, in_g, winh, winl, nullptr, DDIM, 0);
  rownorm_split<<<DDIM, 256, 0, stream>>>(out_v, out_g, wouth, woutl, nullptr, CDIM, 0);
  rownorm_split<<<KDIM, 256, 0, stream>>>(cb, nullptr, cbh, cbl, c2, CDIM, 1);

  // z -> zT split (for in_proj B operand)
  transpose_split_z<<<dim3(TDIM / 64, DDIM / 64), 256, 0, stream>>>(z, zth, ztl);

  // z_e = W_in @ z + in_b  (split-bf16 MFMA, BN=64, K=1024)
  gemm_mfma_in<<<dim3(TDIM / 64, CDIM / 128), 256, 0, stream>>>(
      winh, winl, zth, ztl, in_b, z_e, DDIM);

  // fused colnorm + transpose + split -> eth/etl [t][c]
  finish_ze<<<TDIM / 32, 256, 0, stream>>>(z_e, eth, etl);

  // nearest-codebook argmin (k-split x8), gload_lds A + direct-B structure
  dist_mfma<<<dim3(TDIM / 128, KSPLIT), 512, 0, stream>>>(eth, etl, cbh, cbl, c2, pv, pi);
  merge_argmin<<<TDIM / 256, 256, 0, stream>>>(pv, pi, idxw, idxf);

  // zq = cb[idx] -> split [t][c]
  gather_split<<<TDIM / 4, 256, 0, stream>>>(idxw, cb, zqh, zql);

  // out = W_out @ z_q + out_b  (split-bf16 MFMA, K=256)
  gemm_mfma_bias<<<dim3(TDIM / 128, DDIM / 128), 256, 0, stream>>>(
      wouth, woutl, zqh, zql, out_b, outp, CDIM);
}

// Round 3
// 434.481 us; speedup vs baseline: 1.3196x; 1.3196x over previous
//
#include <hip/hip_runtime.h>
#include <hip/hip_bf16.h>
#include <math.h>

#define TDIM 16384
#define DDIM 1024
#define CDIM 256
#define KDIM 8192
#define KSPLIT 8

typedef unsigned short u16;
typedef __attribute__((ext_vector_type(8))) short bf16x8;
typedef __attribute__((ext_vector_type(8))) unsigned short us8;
typedef __attribute__((ext_vector_type(4))) float floatx4;

// ---- workspace layout (float offsets) ----
static const size_t OFF_WINH  = 0;                                     // 256x1024 u16
static const size_t OFF_WINL  = OFF_WINH  + (size_t)CDIM * DDIM / 2;
static const size_t OFF_WOUTH = OFF_WINL  + (size_t)CDIM * DDIM / 2;   // 1024x256 u16
static const size_t OFF_WOUTL = OFF_WOUTH + (size_t)DDIM * CDIM / 2;
static const size_t OFF_CBH   = OFF_WOUTL + (size_t)DDIM * CDIM / 2;   // 8192x256 u16
static const size_t OFF_CBL   = OFF_CBH   + (size_t)KDIM * CDIM / 2;
static const size_t OFF_C2    = OFF_CBL   + (size_t)KDIM * CDIM / 2;   // 8192 f32
static const size_t OFF_ZTH   = OFF_C2    + (size_t)KDIM;              // 16384x1024 u16 [t][d]
static const size_t OFF_ZTL   = OFF_ZTH   + (size_t)TDIM * DDIM / 2;
static const size_t OFF_ZE    = OFF_ZTL   + (size_t)TDIM * DDIM / 2;   // 256x16384 f32
static const size_t OFF_PV    = OFF_ZE    + (size_t)CDIM * TDIM;       // 8x16384 f32
static const size_t OFF_PI    = OFF_PV    + (size_t)KSPLIT * TDIM;     // 8x16384 i32
static const size_t OFF_IDX   = OFF_PI    + (size_t)KSPLIT * TDIM;     // 16384 i32
// eth/etl [t][c] alias ZTH (zth/ztl dead after in_proj gemm);
// zqh/zql alias the same region again (eth/etl dead after dist_mfma).
static const size_t OFF_ETH   = OFF_ZTH;
static const size_t OFF_ETL   = OFF_ZTH + (size_t)TDIM * CDIM / 2;

static __device__ __forceinline__ u16 f2bf(float x) {
  __hip_bfloat16 h = __float2bfloat16(x);
  return *(u16*)&h;
}
static __device__ __forceinline__ float bf2f(u16 u) {
  __hip_bfloat16 h; *(u16*)&h = u;
  return __bfloat162float(h);
}

// async global->LDS 16B copy (LDS dest = wave-uniform base + lane*16;
// our per-lane dests are consecutive-16B by construction).
static __device__ __forceinline__ void gload16(const u16* g, u16* l) {
  __builtin_amdgcn_global_load_lds(
      (__attribute__((address_space(1))) void*)g,
      (__attribute__((address_space(3))) void*)l, 16, 0, 0);
}

// ---------------------------------------------------------------------------
// Row-wise L2 normalize -> bf16 hi/lo split. Optional g, clip, c2.
// ---------------------------------------------------------------------------
__global__ __launch_bounds__(256) void rownorm_split(
    const float* __restrict__ v, const float* __restrict__ g,
    u16* __restrict__ hi, u16* __restrict__ lo, float* __restrict__ c2,
    int ncols, int clip) {
  __shared__ float red[256];
  int row = blockIdx.x;
  const float* vr = v + (size_t)row * ncols;
  float s = 0.f;
  for (int j = threadIdx.x; j < ncols; j += 256) { float x = vr[j]; s += x * x; }
  red[threadIdx.x] = s;
  __syncthreads();
  for (int off = 128; off > 0; off >>= 1) {
    if (threadIdx.x < off) red[threadIdx.x] += red[threadIdx.x + off];
    __syncthreads();
  }
  float norm = sqrtf(red[0]);
  if (clip) norm = fmaxf(norm, 1e-12f);
  float scale = (g ? g[row] : 1.0f) / norm;
  float s2 = 0.f;
  for (int j = threadIdx.x; j < ncols; j += 256) {
    float y = vr[j] * scale;
    u16 hh = f2bf(y);
    u16 ll = f2bf(y - bf2f(hh));
    hi[(size_t)row * ncols + j] = hh;
    lo[(size_t)row * ncols + j] = ll;
    s2 += y * y;
  }
  if (c2) {
    __syncthreads();
    red[threadIdx.x] = s2;
    __syncthreads();
    for (int off = 128; off > 0; off >>= 1) {
      if (threadIdx.x < off) red[threadIdx.x] += red[threadIdx.x + off];
      __syncthreads();
    }
    if (threadIdx.x == 0) c2[row] = red[0];
  }
}

// ---------------------------------------------------------------------------
// z [d][t] fp32 -> zth/ztl [t][d] bf16 hi/lo (LDS 64x64 tile transpose)
// ---------------------------------------------------------------------------
__global__ __launch_bounds__(256) void transpose_split_z(
    const float* __restrict__ z, u16* __restrict__ zth, u16* __restrict__ ztl) {
  __shared__ float tile[64][65];
  int t0 = blockIdx.x * 64, d0 = blockIdx.y * 64;
  int tl = threadIdx.x & 63, grp = threadIdx.x >> 6;
#pragma unroll
  for (int r = 0; r < 16; r++) {
    int d = grp * 16 + r;
    tile[d][tl] = z[(size_t)(d0 + d) * TDIM + t0 + tl];
  }
  __syncthreads();
#pragma unroll
  for (int r = 0; r < 16; r++) {
    int t = grp * 16 + r;
    float x = tile[tl][t];
    u16 h = f2bf(x);
    u16 l = f2bf(x - bf2f(h));
    zth[(size_t)(t0 + t) * DDIM + d0 + tl] = h;
    ztl[(size_t)(t0 + t) * DDIM + d0 + tl] = l;
  }
}

// ---------------------------------------------------------------------------
// in_proj split-bf16 MFMA GEMM, BN=64: C[m][t] = A[m]·B[t] + bias[m]
// ---------------------------------------------------------------------------
__global__ __launch_bounds__(256) void gemm_mfma_in(
    const u16* __restrict__ ah_g, const u16* __restrict__ al_g,
    const u16* __restrict__ bh_g, const u16* __restrict__ bl_g,
    const float* __restrict__ bias, float* __restrict__ C, int K) {
  __shared__ u16 Ah[128 * 32], Al[128 * 32];
  __shared__ u16 Bh[64 * 32],  Bl[64 * 32];
  int tid = threadIdx.x;
  int n0 = blockIdx.x * 64;      // t
  int m0 = blockIdx.y * 128;     // output rows
  int lane = tid & 63, wid = tid >> 6;
  int wr = wid >> 1, wc = wid & 1;
  int q = lane >> 4, mm = lane & 15;
  int h = tid & 1;
  int sr = ((tid >> 1) ^ (h << 2)) & 127;
  int ssw = (sr ^ (sr >> 2)) & 3;
  int o0 = sr * 32 + ((((h << 1))     ^ ssw) << 3);
  int o1 = sr * 32 + ((((h << 1) | 1) ^ ssw) << 3);
  int gcol = h * 16;
  // B staging (64 rows): threads tid<128 cover 64 rows x 2 halves
  int sb = ((tid >> 1) ^ (h << 2)) & 63;
  int ssb = (sb ^ (sb >> 2)) & 3;
  int p0 = sb * 32 + ((((h << 1))     ^ ssb) << 3);
  int p1 = sb * 32 + ((((h << 1) | 1) ^ ssb) << 3);
  int sm = (mm ^ (mm >> 2)) & 3;
  int cq = (q ^ sm) << 3;

  const floatx4 z4 = {0.f, 0.f, 0.f, 0.f};
  floatx4 acc[4][2];
#pragma unroll
  for (int i = 0; i < 4; i++)
#pragma unroll
    for (int j = 0; j < 2; j++) acc[i][j] = z4;

  for (int c0 = 0; c0 < K; c0 += 32) {
    const size_t ga = (size_t)(m0 + sr) * K + c0 + gcol;
    us8 a_h0 = *(const us8*)&ah_g[ga];
    us8 a_h1 = *(const us8*)&ah_g[ga + 8];
    us8 a_l0 = *(const us8*)&al_g[ga];
    us8 a_l1 = *(const us8*)&al_g[ga + 8];
    us8 b_h0, b_h1, b_l0, b_l1;
    if (tid < 128) {
      const size_t gb = (size_t)(n0 + sb) * K + c0 + gcol;
      b_h0 = *(const us8*)&bh_g[gb];
      b_h1 = *(const us8*)&bh_g[gb + 8];
      b_l0 = *(const us8*)&bl_g[gb];
      b_l1 = *(const us8*)&bl_g[gb + 8];
    }
    __syncthreads();
    *(us8*)&Ah[o0] = a_h0; *(us8*)&Ah[o1] = a_h1;
    *(us8*)&Al[o0] = a_l0; *(us8*)&Al[o1] = a_l1;
    if (tid < 128) {
      *(us8*)&Bh[p0] = b_h0; *(us8*)&Bh[p1] = b_h1;
      *(us8*)&Bl[p0] = b_l0; *(us8*)&Bl[p1] = b_l1;
    }
    __syncthreads();

    bf16x8 fa[4], fb[2];
#pragma unroll
    for (int i = 0; i < 4; i++)
      fa[i] = *(const bf16x8*)&Ah[(wr * 64 + i * 16 + mm) * 32 + cq];
#pragma unroll
    for (int j = 0; j < 2; j++)
      fb[j] = *(const bf16x8*)&Bh[(wc * 32 + j * 16 + mm) * 32 + cq];
#pragma unroll
    for (int i = 0; i < 4; i++)
#pragma unroll
      for (int j = 0; j < 2; j++)
        acc[i][j] = __builtin_amdgcn_mfma_f32_16x16x32_bf16(fa[i], fb[j], acc[i][j], 0, 0, 0);
#pragma unroll
    for (int i = 0; i < 4; i++) {
      bf16x8 fl = *(const bf16x8*)&Al[(wr * 64 + i * 16 + mm) * 32 + cq];
#pragma unroll
      for (int j = 0; j < 2; j++)
        acc[i][j] = __builtin_amdgcn_mfma_f32_16x16x32_bf16(fl, fb[j], acc[i][j], 0, 0, 0);
    }
#pragma unroll
    for (int j = 0; j < 2; j++) {
      bf16x8 fl = *(const bf16x8*)&Bl[(wc * 32 + j * 16 + mm) * 32 + cq];
#pragma unroll
      for (int i = 0; i < 4; i++)
        acc[i][j] = __builtin_amdgcn_mfma_f32_16x16x32_bf16(fa[i], fl, acc[i][j], 0, 0, 0);
    }
  }

#pragma unroll
  for (int i = 0; i < 4; i++) {
#pragma unroll
    for (int r = 0; r < 4; r++) {
      int m_loc = wr * 64 + i * 16 + q * 4 + r;
      float bb = bias[m0 + m_loc];
      float* crow = &C[(size_t)(m0 + m_loc) * TDIM + n0 + wc * 32 + mm];
#pragma unroll
      for (int j = 0; j < 2; j++) crow[j * 16] = acc[i][j][r] + bb;
    }
  }
}

// ---------------------------------------------------------------------------
// out_proj split-bf16 MFMA GEMM + bias, BN=128 (R6/R7-verified).
// ---------------------------------------------------------------------------
__global__ __launch_bounds__(256) void gemm_mfma_bias(
    const u16* __restrict__ ah_g, const u16* __restrict__ al_g,
    const u16* __restrict__ bh_g, const u16* __restrict__ bl_g,
    const float* __restrict__ bias, float* __restrict__ C, int K) {
  __shared__ u16 Ah[128 * 32], Al[128 * 32];
  __shared__ u16 Bh[128 * 32], Bl[128 * 32];
  int tid = threadIdx.x;
  int n0 = blockIdx.x * 128;
  int m0 = blockIdx.y * 128;
  int lane = tid & 63, wid = tid >> 6;
  int wr = wid >> 1, wc = wid & 1;
  int q = lane >> 4, mm = lane & 15;
  int h = tid & 1;
  int sr = ((tid >> 1) ^ (h << 2)) & 127;
  int ssw = (sr ^ (sr >> 2)) & 3;
  int o0 = sr * 32 + ((((h << 1))     ^ ssw) << 3);
  int o1 = sr * 32 + ((((h << 1) | 1) ^ ssw) << 3);
  int gcol = h * 16;
  int sm = (mm ^ (mm >> 2)) & 3;
  int cq = (q ^ sm) << 3;

  const floatx4 z4 = {0.f, 0.f, 0.f, 0.f};
  floatx4 acc[4][4];
#pragma unroll
  for (int i = 0; i < 4; i++)
#pragma unroll
    for (int j = 0; j < 4; j++) acc[i][j] = z4;

  for (int c0 = 0; c0 < K; c0 += 32) {
    const size_t ga = (size_t)(m0 + sr) * K + c0 + gcol;
    const size_t gb = (size_t)(n0 + sr) * K + c0 + gcol;
    us8 a_h0 = *(const us8*)&ah_g[ga];
    us8 a_h1 = *(const us8*)&ah_g[ga + 8];
    us8 a_l0 = *(const us8*)&al_g[ga];
    us8 a_l1 = *(const us8*)&al_g[ga + 8];
    us8 b_h0 = *(const us8*)&bh_g[gb];
    us8 b_h1 = *(const us8*)&bh_g[gb + 8];
    us8 b_l0 = *(const us8*)&bl_g[gb];
    us8 b_l1 = *(const us8*)&bl_g[gb + 8];
    __syncthreads();
    *(us8*)&Ah[o0] = a_h0; *(us8*)&Ah[o1] = a_h1;
    *(us8*)&Al[o0] = a_l0; *(us8*)&Al[o1] = a_l1;
    *(us8*)&Bh[o0] = b_h0; *(us8*)&Bh[o1] = b_h1;
    *(us8*)&Bl[o0] = b_l0; *(us8*)&Bl[o1] = b_l1;
    __syncthreads();

    bf16x8 fa[4], fb[4];
#pragma unroll
    for (int i = 0; i < 4; i++)
      fa[i] = *(const bf16x8*)&Ah[(wr * 64 + i * 16 + mm) * 32 + cq];
#pragma unroll
    for (int j = 0; j < 4; j++)
      fb[j] = *(const bf16x8*)&Bh[(wc * 64 + j * 16 + mm) * 32 + cq];
#pragma unroll
    for (int i = 0; i < 4; i++)
#pragma unroll
      for (int j = 0; j < 4; j++)
        acc[i][j] = __builtin_amdgcn_mfma_f32_16x16x32_bf16(fa[i], fb[j], acc[i][j], 0, 0, 0);
#pragma unroll
    for (int i = 0; i < 4; i++) {
      bf16x8 fl = *(const bf16x8*)&Al[(wr * 64 + i * 16 + mm) * 32 + cq];
#pragma unroll
      for (int j = 0; j < 4; j++)
        acc[i][j] = __builtin_amdgcn_mfma_f32_16x16x32_bf16(fl, fb[j], acc[i][j], 0, 0, 0);
    }
#pragma unroll
    for (int j = 0; j < 4; j++) {
      bf16x8 fl = *(const bf16x8*)&Bl[(wc * 64 + j * 16 + mm) * 32 + cq];
#pragma unroll
      for (int i = 0; i < 4; i++)
        acc[i][j] = __builtin_amdgcn_mfma_f32_16x16x32_bf16(fa[i], fl, acc[i][j], 0, 0, 0);
    }
  }

#pragma unroll
  for (int i = 0; i < 4; i++) {
#pragma unroll
    for (int r = 0; r < 4; r++) {
      int m_loc = wr * 64 + i * 16 + q * 4 + r;
      float bb = bias[m0 + m_loc];
      float* crow = &C[(size_t)(m0 + m_loc) * TDIM + n0 + wc * 64 + mm];
#pragma unroll
      for (int j = 0; j < 4; j++) crow[j * 16] = acc[i][j][r] + bb;
    }
  }
}

// ---------------------------------------------------------------------------
// finish_ze: fused column-norm + transpose + bf16 split, 32-t tiles.
// ---------------------------------------------------------------------------
__global__ __launch_bounds__(256) void finish_ze(
    const float* __restrict__ ze, u16* __restrict__ eth, u16* __restrict__ etl) {
  __shared__ float tile[256][33];
  __shared__ float red[8][32];
  __shared__ float invs[32];
  int t0 = blockIdx.x * 32;
  int tl = threadIdx.x & 31, grp = threadIdx.x >> 5;
  float s = 0.f;
  for (int c = grp * 32; c < grp * 32 + 32; c++) {
    float v = ze[(size_t)c * TDIM + t0 + tl];
    tile[c][tl] = v;
    s += v * v;
  }
  red[grp][tl] = s;
  __syncthreads();
  if (grp == 0) {
    float tot = 0.f;
#pragma unroll
    for (int gg = 0; gg < 8; gg++) tot += red[gg][tl];
    invs[tl] = 1.0f / fmaxf(sqrtf(tot), 1e-12f);
  }
  __syncthreads();
#pragma unroll
  for (int r = 0; r < 4; r++) {
    int t = grp * 4 + r;
    float iv = invs[t];
#pragma unroll
    for (int cc = 0; cc < 8; cc++) {
      int cd = cc * 32 + tl;
      float x = tile[cd][t] * iv;
      u16 hh = f2bf(x);
      u16 ll = f2bf(x - bf2f(hh));
      eth[(size_t)(t0 + t) * CDIM + cd] = hh;
      etl[(size_t)(t0 + t) * CDIM + cd] = ll;
    }
  }
}

// ---------------------------------------------------------------------------
// dist + argmin via split-bf16 MFMA — R10:
//   - Bh (enc hi, [128t][256c]) PERSISTENT in LDS (64KB), staged once via
//     gload_lds with octet-permutation XOR: physical granule = logical ^
//     (row&7) in 512B rows. Read slot = (cc*8+kk*4+q)^(mm&7): exact
//     permutation of 0..7 within every consecutive-8-lane octet -> 0 conflicts
//     (R8's sm5 swizzle was even globally but 2-way within octets).
//   - Bl (enc lo) PERSISTENT IN REGISTERS: 16 bf16x8/wave (wave t-tile 32),
//     loaded once; statically indexed via unrolled cc/kk. Zero Bl LDS traffic,
//     zero per-chunk B global traffic (R9's regression).
//   - A (codebook) hi/lo via R9-verified gload_lds dbuf: k-step 128, BK=64,
//     granule XOR (g ^= row&7), 64KB total, 1 barrier/chunk, prefetch issued
//     before the MFMA cluster (covered by ~1.9Kcy/SIMD of MFMA).
//   - Waves 2k x 4t, wave tile 64k x 32t, acc[4][2].
// Per-(t,k) FMA sequence (c0 ascending by 32; per c0: hihi, lohi, hilo; fp32
// MFMA accumulate) IDENTICAL to verified kernels -> dist/indices bit-equal.
// LDS 130KB -> 1 block/CU, 8 waves (2/SIMD). VGPR ~150 (no spill).
// ---------------------------------------------------------------------------
__global__ __launch_bounds__(512, 2) void dist_mfma(
    const u16* __restrict__ eth, const u16* __restrict__ etl,
    const u16* __restrict__ cbh, const u16* __restrict__ cbl,
    const float* __restrict__ c2, float* __restrict__ pv, int* __restrict__ pi) {
  __shared__ u16 BhL[128 * 256];     // 64 KB persistent enc-hi
  __shared__ u16 AhL[2][128 * 64];   // 32 KB codebook-hi dbuf
  __shared__ u16 AlL[2][128 * 64];   // 32 KB codebook-lo dbuf
  __shared__ float mv[2][128];
  __shared__ int   mi[2][128];

  int tid = threadIdx.x;
  int t0 = blockIdx.x * 128;
  int kbeg = blockIdx.y * (KDIM / KSPLIT);
  int lane = tid & 63, wid = tid >> 6;
  int wk = wid >> 2, wt = wid & 3;       // 2 waves along k, 4 along t
  int q = lane >> 4, mm = lane & 15;

  // A staging constants: thread covers granule gi = it*512+tid (it=0..1);
  // LDS linear pos gi holds source granule (gi&7)^(row&7) of the chunk.
  int stR[2], stC[2], stL[2];
#pragma unroll
  for (int it = 0; it < 2; it++) {
    int gi = it * 512 + tid;
    int r = gi >> 3, g = gi & 7;
    stR[it] = r;                         // 0..127
    stC[it] = (g ^ (r & 7)) << 3;        // u16 col offset within 64-col chunk
    stL[it] = gi << 3;                   // u16 linear LDS offset
  }

  // A-fragment read offsets (octet-permutation swizzle), per kk
  int foff[2];
#pragma unroll
  for (int kk = 0; kk < 2; kk++)
    foff[kk] = ((((kk << 2) | q) ^ (mm & 7)) << 3);

  // ---- prologue: persistent Bh stage (gload_lds, octet-perm layout) ----
#pragma unroll
  for (int it = 0; it < 8; ++it) {
    int gi = it * 512 + tid;             // 0..4095
    int r = gi >> 5, p = gi & 31;
    gload16(&eth[(size_t)(t0 + r) * CDIM + ((p ^ (r & 7)) << 3)], &BhL[gi << 3]);
  }
  // ---- persistent Bl -> registers (once) ----
  bf16x8 fbl[2][8];
#pragma unroll
  for (int j = 0; j < 2; ++j)
#pragma unroll
    for (int sl = 0; sl < 8; ++sl)
      fbl[j][sl] = *(const bf16x8*)
          &etl[(size_t)(t0 + wt * 32 + j * 16 + mm) * CDIM + sl * 32 + q * 8];
  // ---- A chunk 0 stage into buf 0 ----
#pragma unroll
  for (int it = 0; it < 2; ++it) {
    const size_t ga = (size_t)(kbeg + stR[it]) * CDIM + stC[it];
    gload16(&cbh[ga], &AhL[0][stL[it]]);
    gload16(&cbl[ga], &AlL[0][stL[it]]);
  }

  float rbv[2]; int rbi[2];
#pragma unroll
  for (int j = 0; j < 2; j++) { rbv[j] = INFINITY; rbi[j] = 0x7fffffff; }

  const floatx4 z4 = {0.f, 0.f, 0.f, 0.f};
  floatx4 acc[4][2];
#pragma unroll
  for (int i = 0; i < 4; i++)
#pragma unroll
    for (int j = 0; j < 2; j++) acc[i][j] = z4;

  for (int ks = 0; ks < 8; ++ks) {       // 8 k-steps of 128 rows
#pragma unroll
    for (int cc = 0; cc < 4; ++cc) {     // 4 chunks of BK=64
      const int b = cc & 1;
      __syncthreads();                   // drains prev prefetch; guards buf reuse

      // prefetch next chunk into the other buffer (lands under MFMAs)
      int nglob = ks * 4 + cc;
      if (nglob < 31) {
        int n1 = nglob + 1;
        int k0n = kbeg + (n1 >> 2) * 128;
        int c0n = (n1 & 3) * 64;
#pragma unroll
        for (int it = 0; it < 2; ++it) {
          const size_t ga = (size_t)(k0n + stR[it]) * CDIM + c0n + stC[it];
          gload16(&cbh[ga], &AhL[b ^ 1][stL[it]]);
          gload16(&cbl[ga], &AlL[b ^ 1][stL[it]]);
        }
      }

      // MFMA cluster: per 32-col slice (kk): hihi -> lohi -> hilo
#pragma unroll
      for (int kk = 0; kk < 2; ++kk) {
        bf16x8 fah[4], fbh[2];
#pragma unroll
        for (int i = 0; i < 4; i++)
          fah[i] = *(const bf16x8*)&AhL[b][(wk * 64 + i * 16 + mm) * 64 + foff[kk]];
#pragma unroll
        for (int j = 0; j < 2; j++)
          fbh[j] = *(const bf16x8*)&BhL[(wt * 32 + j * 16 + mm) * 256 +
                                        (((cc * 8 + kk * 4 + q) ^ (mm & 7)) << 3)];
#pragma unroll
        for (int i = 0; i < 4; i++)
#pragma unroll
          for (int j = 0; j < 2; j++)
            acc[i][j] = __builtin_amdgcn_mfma_f32_16x16x32_bf16(fah[i], fbh[j], acc[i][j], 0, 0, 0);
#pragma unroll
        for (int i = 0; i < 4; i++) {
          bf16x8 fl = *(const bf16x8*)&AlL[b][(wk * 64 + i * 16 + mm) * 64 + foff[kk]];
#pragma unroll
          for (int j = 0; j < 2; j++)
            acc[i][j] = __builtin_amdgcn_mfma_f32_16x16x32_bf16(fl, fbh[j], acc[i][j], 0, 0, 0);
        }
#pragma unroll
        for (int j = 0; j < 2; j++) {
#pragma unroll
          for (int i = 0; i < 4; i++)
            acc[i][j] = __builtin_amdgcn_mfma_f32_16x16x32_bf16(fah[i], fbl[j][cc * 2 + kk], acc[i][j], 0, 0, 0);
        }
      }
    }

    // k-step epilogue: fold acc into running argmin, reset acc
    int k0 = kbeg + ks * 128;
#pragma unroll
    for (int i = 0; i < 4; i++) {
#pragma unroll
      for (int r4 = 0; r4 < 4; r4++) {
        int kg = k0 + wk * 64 + i * 16 + q * 4 + r4;
        float c2v = c2[kg];
#pragma unroll
        for (int j = 0; j < 2; j++) {
          float s = c2v - 2.0f * acc[i][j][r4];
          if (s < rbv[j]) { rbv[j] = s; rbi[j] = kg; }
        }
      }
    }
#pragma unroll
    for (int i = 0; i < 4; i++)
#pragma unroll
      for (int j = 0; j < 2; j++) acc[i][j] = z4;
  }

  // cross-lane reduce over q (lanes 16/32 apart hold same t)
#pragma unroll
  for (int j = 0; j < 2; j++) {
    float v = rbv[j]; int ii = rbi[j];
    float ov = __shfl_xor(v, 16, 64); int oi = __shfl_xor(ii, 16, 64);
    if (ov < v || (ov == v && oi < ii)) { v = ov; ii = oi; }
    ov = __shfl_xor(v, 32, 64); oi = __shfl_xor(ii, 32, 64);
    if (ov < v || (ov == v && oi < ii)) { v = ov; ii = oi; }
    rbv[j] = v; rbi[j] = ii;
  }
  __syncthreads();   // BhL reads done before mv/mi (aliasing-safe ordering)
  if (q == 0) {
#pragma unroll
    for (int j = 0; j < 2; j++) {
      mv[wk][wt * 32 + j * 16 + mm] = rbv[j];
      mi[wk][wt * 32 + j * 16 + mm] = rbi[j];
    }
  }
  __syncthreads();
  if (tid < 128) {
    float v0 = mv[0][tid]; int i0 = mi[0][tid];
    float v1 = mv[1][tid]; int i1 = mi[1][tid];
    if (v1 < v0 || (v1 == v0 && i1 < i0)) { v0 = v1; i0 = i1; }
    pv[(size_t)blockIdx.y * TDIM + t0 + tid] = v0;
    pi[(size_t)blockIdx.y * TDIM + t0 + tid] = i0;
  }
}

// ---------------------------------------------------------------------------
// merge k-splits; emit int idx (for gather) and float idx (output 1)
// ---------------------------------------------------------------------------
__global__ __launch_bounds__(256) void merge_argmin(
    const float* __restrict__ pv, const int* __restrict__ pi,
    int* __restrict__ idx, float* __restrict__ idxf) {
  int t = blockIdx.x * 256 + threadIdx.x;
  float bv = INFINITY; int bi = 0x7fffffff;
  for (int s = 0; s < KSPLIT; s++) {
    float v = pv[(size_t)s * TDIM + t];
    int ii = pi[(size_t)s * TDIM + t];
    if (v < bv || (v == bv && ii < bi)) { bv = v; bi = ii; }
  }
  idx[t] = bi;
  idxf[t] = (float)bi;
}

// ---------------------------------------------------------------------------
// gather: zqT[t][c] = split(cb[idx[t]][c]); 4 t per block, float4 loads.
// ---------------------------------------------------------------------------
__global__ __launch_bounds__(256) void gather_split(
    const int* __restrict__ idx, const float* __restrict__ cb,
    u16* __restrict__ zqh, u16* __restrict__ zql) {
  int t = blockIdx.x * 4 + (threadIdx.x >> 6);
  int c4 = (threadIdx.x & 63) * 4;
  int k = idx[t];
  float4 x = *(const float4*)&cb[(size_t)k * CDIM + c4];
  u16 h0 = f2bf(x.x), h1 = f2bf(x.y), h2 = f2bf(x.z), h3 = f2bf(x.w);
  u16 l0 = f2bf(x.x - bf2f(h0)), l1 = f2bf(x.y - bf2f(h1));
  u16 l2 = f2bf(x.z - bf2f(h2)), l3 = f2bf(x.w - bf2f(h3));
  ushort4 hv = {h0, h1, h2, h3}, lv = {l0, l1, l2, l3};
  *(ushort4*)&zqh[(size_t)t * CDIM + c4] = hv;
  *(ushort4*)&zql[(size_t)t * CDIM + c4] = lv;
}

extern "C" void kernel_launch(void* const* d_in, const int* in_sizes, int n_in,
                              void* d_out, int out_size, void* d_ws, size_t ws_size,
                              hipStream_t stream) {
  const float* z     = (const float*)d_in[0];
  const float* in_v  = (const float*)d_in[1];
  const float* in_g  = (const float*)d_in[2];
  const float* in_b  = (const float*)d_in[3];
  const float* out_v = (const float*)d_in[4];
  const float* out_g = (const float*)d_in[5];
  const float* out_b = (const float*)d_in[6];
  const float* cb    = (const float*)d_in[7];

  float* ws    = (float*)d_ws;
  u16*   winh  = (u16*)(ws + OFF_WINH);
  u16*   winl  = (u16*)(ws + OFF_WINL);
  u16*   wouth = (u16*)(ws + OFF_WOUTH);
  u16*   woutl = (u16*)(ws + OFF_WOUTL);
  u16*   cbh   = (u16*)(ws + OFF_CBH);
  u16*   cbl   = (u16*)(ws + OFF_CBL);
  float* c2    = ws + OFF_C2;
  u16*   zth   = (u16*)(ws + OFF_ZTH);
  u16*   ztl   = (u16*)(ws + OFF_ZTL);
  float* z_e   = ws + OFF_ZE;
  float* pv    = ws + OFF_PV;
  int*   pi    = (int*)(ws + OFF_PI);
  int*   idxw  = (int*)(ws + OFF_IDX);
  u16*   eth   = (u16*)(ws + OFF_ETH);   // aliases zth (dead after in_proj)
  u16*   etl   = (u16*)(ws + OFF_ETL);
  u16*   zqh   = eth;                    // aliases eth (dead after dist)
  u16*   zql   = etl;

  float* outp = (float*)d_out;                 // (1024 x 16384) fp32
  float* idxf = outp + (size_t)DDIM * TDIM;    // indices as float32

  // weight prep: all weights emitted directly as split-bf16
  rownorm_split<<<CDIM, 256, 0, stream>>>(in_v, in_g, winh, winl, nullptr, DDIM, 0);
  rownorm_split<<<DDIM, 256, 0, stream>>>(out_v, out_g, wouth, woutl, nullptr, CDIM, 0);
  rownorm_split<<<KDIM, 256, 0, stream>>>(cb, nullptr, cbh, cbl, c2, CDIM, 1);

  // z -> zT split (for in_proj B operand)
  transpose_split_z<<<dim3(TDIM / 64, DDIM / 64), 256, 0, stream>>>(z, zth, ztl);

  // z_e = W_in @ z + in_b  (split-bf16 MFMA, BN=64, K=1024)
  gemm_mfma_in<<<dim3(TDIM / 64, CDIM / 128), 256, 0, stream>>>(
      winh, winl, zth, ztl, in_b, z_e, DDIM);

  // fused colnorm + transpose + split -> eth/etl [t][c]
  finish_ze<<<TDIM / 32, 256, 0, stream>>>(z_e, eth, etl);

  // nearest-codebook argmin (k-split x8): Bh-LDS + Bl-regs + gload_lds A
  dist_mfma<<<dim3(TDIM / 128, KSPLIT), 512, 0, stream>>>(eth, etl, cbh, cbl, c2, pv, pi);
  merge_argmin<<<TDIM / 256, 256, 0, stream>>>(pv, pi, idxw, idxf);

  // zq = cb[idx] -> split [t][c]
  gather_split<<<TDIM / 4, 256, 0, stream>>>(idxw, cb, zqh, zql);

  // out = W_out @ z_q + out_b  (split-bf16 MFMA, K=256)
  gemm_mfma_bias<<<dim3(TDIM / 128, DDIM / 128), 256, 0, stream>>>(
      wouth, woutl, zqh, zql, out_b, outp, CDIM);
}

// Round 4
// 432.715 us; speedup vs baseline: 1.3250x; 1.0041x over previous
//
#include <hip/hip_runtime.h>
#include <hip/hip_bf16.h>
#include <math.h>

#define TDIM 16384
#define DDIM 1024
#define CDIM 256
#define KDIM 8192
#define KSPLIT 8

typedef unsigned short u16;
typedef __attribute__((ext_vector_type(8))) short bf16x8;
typedef __attribute__((ext_vector_type(8))) unsigned short us8;
typedef __attribute__((ext_vector_type(4))) float floatx4;

// ---- workspace layout (float offsets) ----
static const size_t OFF_WINH  = 0;                                     // 256x1024 u16
static const size_t OFF_WINL  = OFF_WINH  + (size_t)CDIM * DDIM / 2;
static const size_t OFF_WOUTH = OFF_WINL  + (size_t)CDIM * DDIM / 2;   // 1024x256 u16
static const size_t OFF_WOUTL = OFF_WOUTH + (size_t)DDIM * CDIM / 2;
static const size_t OFF_CBH   = OFF_WOUTL + (size_t)DDIM * CDIM / 2;   // 8192x256 u16
static const size_t OFF_CBL   = OFF_CBH   + (size_t)KDIM * CDIM / 2;
static const size_t OFF_C2    = OFF_CBL   + (size_t)KDIM * CDIM / 2;   // 8192 f32
static const size_t OFF_ZTH   = OFF_C2    + (size_t)KDIM;              // 16384x1024 u16 [t][d]
static const size_t OFF_ZTL   = OFF_ZTH   + (size_t)TDIM * DDIM / 2;
static const size_t OFF_ZE    = OFF_ZTL   + (size_t)TDIM * DDIM / 2;   // 256x16384 f32
static const size_t OFF_PV    = OFF_ZE    + (size_t)CDIM * TDIM;       // 8x16384 f32
static const size_t OFF_PI    = OFF_PV    + (size_t)KSPLIT * TDIM;     // 8x16384 i32
static const size_t OFF_IDX   = OFF_PI    + (size_t)KSPLIT * TDIM;     // 16384 i32
// eth/etl [t][c] alias ZTH (zth/ztl dead after in_proj gemm);
// zqh/zql alias the same region again (eth/etl dead after dist_mfma).
static const size_t OFF_ETH   = OFF_ZTH;
static const size_t OFF_ETL   = OFF_ZTH + (size_t)TDIM * CDIM / 2;

static __device__ __forceinline__ u16 f2bf(float x) {
  __hip_bfloat16 h = __float2bfloat16(x);
  return *(u16*)&h;
}
static __device__ __forceinline__ float bf2f(u16 u) {
  __hip_bfloat16 h; *(u16*)&h = u;
  return __bfloat162float(h);
}

// async global->LDS 16B copy (LDS dest = wave-uniform base + lane*16;
// our per-lane dests are consecutive-16B by construction).
static __device__ __forceinline__ void gload16(const u16* g, u16* l) {
  __builtin_amdgcn_global_load_lds(
      (__attribute__((address_space(1))) void*)g,
      (__attribute__((address_space(3))) void*)l, 16, 0, 0);
}

// ---------------------------------------------------------------------------
// Row-wise L2 normalize -> bf16 hi/lo split. Optional g, clip, c2.
// ---------------------------------------------------------------------------
__global__ __launch_bounds__(256) void rownorm_split(
    const float* __restrict__ v, const float* __restrict__ g,
    u16* __restrict__ hi, u16* __restrict__ lo, float* __restrict__ c2,
    int ncols, int clip) {
  __shared__ float red[256];
  int row = blockIdx.x;
  const float* vr = v + (size_t)row * ncols;
  float s = 0.f;
  for (int j = threadIdx.x; j < ncols; j += 256) { float x = vr[j]; s += x * x; }
  red[threadIdx.x] = s;
  __syncthreads();
  for (int off = 128; off > 0; off >>= 1) {
    if (threadIdx.x < off) red[threadIdx.x] += red[threadIdx.x + off];
    __syncthreads();
  }
  float norm = sqrtf(red[0]);
  if (clip) norm = fmaxf(norm, 1e-12f);
  float scale = (g ? g[row] : 1.0f) / norm;
  float s2 = 0.f;
  for (int j = threadIdx.x; j < ncols; j += 256) {
    float y = vr[j] * scale;
    u16 hh = f2bf(y);
    u16 ll = f2bf(y - bf2f(hh));
    hi[(size_t)row * ncols + j] = hh;
    lo[(size_t)row * ncols + j] = ll;
    s2 += y * y;
  }
  if (c2) {
    __syncthreads();
    red[threadIdx.x] = s2;
    __syncthreads();
    for (int off = 128; off > 0; off >>= 1) {
      if (threadIdx.x < off) red[threadIdx.x] += red[threadIdx.x + off];
      __syncthreads();
    }
    if (threadIdx.x == 0) c2[row] = red[0];
  }
}

// ---------------------------------------------------------------------------
// z [d][t] fp32 -> zth/ztl [t][d] bf16 hi/lo (LDS 64x64 tile transpose)
// ---------------------------------------------------------------------------
__global__ __launch_bounds__(256) void transpose_split_z(
    const float* __restrict__ z, u16* __restrict__ zth, u16* __restrict__ ztl) {
  __shared__ float tile[64][65];
  int t0 = blockIdx.x * 64, d0 = blockIdx.y * 64;
  int tl = threadIdx.x & 63, grp = threadIdx.x >> 6;
#pragma unroll
  for (int r = 0; r < 16; r++) {
    int d = grp * 16 + r;
    tile[d][tl] = z[(size_t)(d0 + d) * TDIM + t0 + tl];
  }
  __syncthreads();
#pragma unroll
  for (int r = 0; r < 16; r++) {
    int t = grp * 16 + r;
    float x = tile[tl][t];
    u16 h = f2bf(x);
    u16 l = f2bf(x - bf2f(h));
    zth[(size_t)(t0 + t) * DDIM + d0 + tl] = h;
    ztl[(size_t)(t0 + t) * DDIM + d0 + tl] = l;
  }
}

// ---------------------------------------------------------------------------
// in_proj split-bf16 MFMA GEMM, BN=64: C[m][t] = A[m]·B[t] + bias[m]
// ---------------------------------------------------------------------------
__global__ __launch_bounds__(256) void gemm_mfma_in(
    const u16* __restrict__ ah_g, const u16* __restrict__ al_g,
    const u16* __restrict__ bh_g, const u16* __restrict__ bl_g,
    const float* __restrict__ bias, float* __restrict__ C, int K) {
  __shared__ u16 Ah[128 * 32], Al[128 * 32];
  __shared__ u16 Bh[64 * 32],  Bl[64 * 32];
  int tid = threadIdx.x;
  int n0 = blockIdx.x * 64;      // t
  int m0 = blockIdx.y * 128;     // output rows
  int lane = tid & 63, wid = tid >> 6;
  int wr = wid >> 1, wc = wid & 1;
  int q = lane >> 4, mm = lane & 15;
  int h = tid & 1;
  int sr = ((tid >> 1) ^ (h << 2)) & 127;
  int ssw = (sr ^ (sr >> 2)) & 3;
  int o0 = sr * 32 + ((((h << 1))     ^ ssw) << 3);
  int o1 = sr * 32 + ((((h << 1) | 1) ^ ssw) << 3);
  int gcol = h * 16;
  // B staging (64 rows): threads tid<128 cover 64 rows x 2 halves
  int sb = ((tid >> 1) ^ (h << 2)) & 63;
  int ssb = (sb ^ (sb >> 2)) & 3;
  int p0 = sb * 32 + ((((h << 1))     ^ ssb) << 3);
  int p1 = sb * 32 + ((((h << 1) | 1) ^ ssb) << 3);
  int sm = (mm ^ (mm >> 2)) & 3;
  int cq = (q ^ sm) << 3;

  const floatx4 z4 = {0.f, 0.f, 0.f, 0.f};
  floatx4 acc[4][2];
#pragma unroll
  for (int i = 0; i < 4; i++)
#pragma unroll
    for (int j = 0; j < 2; j++) acc[i][j] = z4;

  for (int c0 = 0; c0 < K; c0 += 32) {
    const size_t ga = (size_t)(m0 + sr) * K + c0 + gcol;
    us8 a_h0 = *(const us8*)&ah_g[ga];
    us8 a_h1 = *(const us8*)&ah_g[ga + 8];
    us8 a_l0 = *(const us8*)&al_g[ga];
    us8 a_l1 = *(const us8*)&al_g[ga + 8];
    us8 b_h0, b_h1, b_l0, b_l1;
    if (tid < 128) {
      const size_t gb = (size_t)(n0 + sb) * K + c0 + gcol;
      b_h0 = *(const us8*)&bh_g[gb];
      b_h1 = *(const us8*)&bh_g[gb + 8];
      b_l0 = *(const us8*)&bl_g[gb];
      b_l1 = *(const us8*)&bl_g[gb + 8];
    }
    __syncthreads();
    *(us8*)&Ah[o0] = a_h0; *(us8*)&Ah[o1] = a_h1;
    *(us8*)&Al[o0] = a_l0; *(us8*)&Al[o1] = a_l1;
    if (tid < 128) {
      *(us8*)&Bh[p0] = b_h0; *(us8*)&Bh[p1] = b_h1;
      *(us8*)&Bl[p0] = b_l0; *(us8*)&Bl[p1] = b_l1;
    }
    __syncthreads();

    bf16x8 fa[4], fb[2];
#pragma unroll
    for (int i = 0; i < 4; i++)
      fa[i] = *(const bf16x8*)&Ah[(wr * 64 + i * 16 + mm) * 32 + cq];
#pragma unroll
    for (int j = 0; j < 2; j++)
      fb[j] = *(const bf16x8*)&Bh[(wc * 32 + j * 16 + mm) * 32 + cq];
#pragma unroll
    for (int i = 0; i < 4; i++)
#pragma unroll
      for (int j = 0; j < 2; j++)
        acc[i][j] = __builtin_amdgcn_mfma_f32_16x16x32_bf16(fa[i], fb[j], acc[i][j], 0, 0, 0);
#pragma unroll
    for (int i = 0; i < 4; i++) {
      bf16x8 fl = *(const bf16x8*)&Al[(wr * 64 + i * 16 + mm) * 32 + cq];
#pragma unroll
      for (int j = 0; j < 2; j++)
        acc[i][j] = __builtin_amdgcn_mfma_f32_16x16x32_bf16(fl, fb[j], acc[i][j], 0, 0, 0);
    }
#pragma unroll
    for (int j = 0; j < 2; j++) {
      bf16x8 fl = *(const bf16x8*)&Bl[(wc * 32 + j * 16 + mm) * 32 + cq];
#pragma unroll
      for (int i = 0; i < 4; i++)
        acc[i][j] = __builtin_amdgcn_mfma_f32_16x16x32_bf16(fa[i], fl, acc[i][j], 0, 0, 0);
    }
  }

#pragma unroll
  for (int i = 0; i < 4; i++) {
#pragma unroll
    for (int r = 0; r < 4; r++) {
      int m_loc = wr * 64 + i * 16 + q * 4 + r;
      float bb = bias[m0 + m_loc];
      float* crow = &C[(size_t)(m0 + m_loc) * TDIM + n0 + wc * 32 + mm];
#pragma unroll
      for (int j = 0; j < 2; j++) crow[j * 16] = acc[i][j][r] + bb;
    }
  }
}

// ---------------------------------------------------------------------------
// out_proj split-bf16 MFMA GEMM + bias, BN=128 (R6/R7-verified).
// ---------------------------------------------------------------------------
__global__ __launch_bounds__(256) void gemm_mfma_bias(
    const u16* __restrict__ ah_g, const u16* __restrict__ al_g,
    const u16* __restrict__ bh_g, const u16* __restrict__ bl_g,
    const float* __restrict__ bias, float* __restrict__ C, int K) {
  __shared__ u16 Ah[128 * 32], Al[128 * 32];
  __shared__ u16 Bh[128 * 32], Bl[128 * 32];
  int tid = threadIdx.x;
  int n0 = blockIdx.x * 128;
  int m0 = blockIdx.y * 128;
  int lane = tid & 63, wid = tid >> 6;
  int wr = wid >> 1, wc = wid & 1;
  int q = lane >> 4, mm = lane & 15;
  int h = tid & 1;
  int sr = ((tid >> 1) ^ (h << 2)) & 127;
  int ssw = (sr ^ (sr >> 2)) & 3;
  int o0 = sr * 32 + ((((h << 1))     ^ ssw) << 3);
  int o1 = sr * 32 + ((((h << 1) | 1) ^ ssw) << 3);
  int gcol = h * 16;
  int sm = (mm ^ (mm >> 2)) & 3;
  int cq = (q ^ sm) << 3;

  const floatx4 z4 = {0.f, 0.f, 0.f, 0.f};
  floatx4 acc[4][4];
#pragma unroll
  for (int i = 0; i < 4; i++)
#pragma unroll
    for (int j = 0; j < 4; j++) acc[i][j] = z4;

  for (int c0 = 0; c0 < K; c0 += 32) {
    const size_t ga = (size_t)(m0 + sr) * K + c0 + gcol;
    const size_t gb = (size_t)(n0 + sr) * K + c0 + gcol;
    us8 a_h0 = *(const us8*)&ah_g[ga];
    us8 a_h1 = *(const us8*)&ah_g[ga + 8];
    us8 a_l0 = *(const us8*)&al_g[ga];
    us8 a_l1 = *(const us8*)&al_g[ga + 8];
    us8 b_h0 = *(const us8*)&bh_g[gb];
    us8 b_h1 = *(const us8*)&bh_g[gb + 8];
    us8 b_l0 = *(const us8*)&bl_g[gb];
    us8 b_l1 = *(const us8*)&bl_g[gb + 8];
    __syncthreads();
    *(us8*)&Ah[o0] = a_h0; *(us8*)&Ah[o1] = a_h1;
    *(us8*)&Al[o0] = a_l0; *(us8*)&Al[o1] = a_l1;
    *(us8*)&Bh[o0] = b_h0; *(us8*)&Bh[o1] = b_h1;
    *(us8*)&Bl[o0] = b_l0; *(us8*)&Bl[o1] = b_l1;
    __syncthreads();

    bf16x8 fa[4], fb[4];
#pragma unroll
    for (int i = 0; i < 4; i++)
      fa[i] = *(const bf16x8*)&Ah[(wr * 64 + i * 16 + mm) * 32 + cq];
#pragma unroll
    for (int j = 0; j < 4; j++)
      fb[j] = *(const bf16x8*)&Bh[(wc * 64 + j * 16 + mm) * 32 + cq];
#pragma unroll
    for (int i = 0; i < 4; i++)
#pragma unroll
      for (int j = 0; j < 4; j++)
        acc[i][j] = __builtin_amdgcn_mfma_f32_16x16x32_bf16(fa[i], fb[j], acc[i][j], 0, 0, 0);
#pragma unroll
    for (int i = 0; i < 4; i++) {
      bf16x8 fl = *(const bf16x8*)&Al[(wr * 64 + i * 16 + mm) * 32 + cq];
#pragma unroll
      for (int j = 0; j < 4; j++)
        acc[i][j] = __builtin_amdgcn_mfma_f32_16x16x32_bf16(fl, fb[j], acc[i][j], 0, 0, 0);
    }
#pragma unroll
    for (int j = 0; j < 4; j++) {
      bf16x8 fl = *(const bf16x8*)&Bl[(wc * 64 + j * 16 + mm) * 32 + cq];
#pragma unroll
      for (int i = 0; i < 4; i++)
        acc[i][j] = __builtin_amdgcn_mfma_f32_16x16x32_bf16(fa[i], fl, acc[i][j], 0, 0, 0);
    }
  }

#pragma unroll
  for (int i = 0; i < 4; i++) {
#pragma unroll
    for (int r = 0; r < 4; r++) {
      int m_loc = wr * 64 + i * 16 + q * 4 + r;
      float bb = bias[m0 + m_loc];
      float* crow = &C[(size_t)(m0 + m_loc) * TDIM + n0 + wc * 64 + mm];
#pragma unroll
      for (int j = 0; j < 4; j++) crow[j * 16] = acc[i][j][r] + bb;
    }
  }
}

// ---------------------------------------------------------------------------
// finish_ze: fused column-norm + transpose + bf16 split, 32-t tiles.
// ---------------------------------------------------------------------------
__global__ __launch_bounds__(256) void finish_ze(
    const float* __restrict__ ze, u16* __restrict__ eth, u16* __restrict__ etl) {
  __shared__ float tile[256][33];
  __shared__ float red[8][32];
  __shared__ float invs[32];
  int t0 = blockIdx.x * 32;
  int tl = threadIdx.x & 31, grp = threadIdx.x >> 5;
  float s = 0.f;
  for (int c = grp * 32; c < grp * 32 + 32; c++) {
    float v = ze[(size_t)c * TDIM + t0 + tl];
    tile[c][tl] = v;
    s += v * v;
  }
  red[grp][tl] = s;
  __syncthreads();
  if (grp == 0) {
    float tot = 0.f;
#pragma unroll
    for (int gg = 0; gg < 8; gg++) tot += red[gg][tl];
    invs[tl] = 1.0f / fmaxf(sqrtf(tot), 1e-12f);
  }
  __syncthreads();
#pragma unroll
  for (int r = 0; r < 4; r++) {
    int t = grp * 4 + r;
    float iv = invs[t];
#pragma unroll
    for (int cc = 0; cc < 8; cc++) {
      int cd = cc * 32 + tl;
      float x = tile[cd][t] * iv;
      u16 hh = f2bf(x);
      u16 ll = f2bf(x - bf2f(hh));
      eth[(size_t)(t0 + t) * CDIM + cd] = hh;
      etl[(size_t)(t0 + t) * CDIM + cd] = ll;
    }
  }
}

// ---------------------------------------------------------------------------
// dist + argmin via split-bf16 MFMA — R11:
//   - B (enc) hi AND lo persistent in REGISTERS: fbh[2][8]+fbl[2][8] =
//     128 VGPR/wave, loaded once in prologue (fbl pattern = R10-verified).
//     ZERO B LDS traffic -> LDS pipe (A-reads only, 49Kcy/block) is now 18%
//     below the MFMA pipe (59.6Kcy/block).
//   - A (codebook) hi/lo: 4-deep gload_lds pipeline (T4 counted-vmcnt),
//     BK=64 chunks, granule XOR (g ^= row&7, R9-verified conflict-free).
//     Per chunk: s_waitcnt vmcnt(8) [3 chunks in flight, never drains] +
//     raw s_barrier + sched_barrier(0); prefetch chunk n+3; setprio(1)
//     around MFMA cluster (T5). Tail issues wrapped dummy prefetches to
//     keep vmcnt arithmetic uniform; final __syncthreads drains them.
//   - c2 staged to LDS in prologue so epilogue c2 reads don't pollute vmcnt.
// Per-(t,k) FMA sequence (cc,kk ascending; hihi -> lohi -> hilo; fp32 MFMA
// accumulate) and wave->tile mapping IDENTICAL to R10 -> dist/indices
// bit-equal. LDS 134KB -> 1 block/CU, 8 waves (2/SIMD).
// ---------------------------------------------------------------------------
__global__ __launch_bounds__(512, 2) void dist_mfma(
    const u16* __restrict__ eth, const u16* __restrict__ etl,
    const u16* __restrict__ cbh, const u16* __restrict__ cbl,
    const float* __restrict__ c2, float* __restrict__ pv, int* __restrict__ pi) {
  __shared__ u16 AhL[4][128 * 64];   // 64 KB codebook-hi quad-buffer
  __shared__ u16 AlL[4][128 * 64];   // 64 KB codebook-lo quad-buffer
  __shared__ float c2L[1024];        // 4 KB block k-range c2
  __shared__ float mv[2][128];
  __shared__ int   mi[2][128];

  int tid = threadIdx.x;
  int t0 = blockIdx.x * 128;
  int kbeg = blockIdx.y * (KDIM / KSPLIT);
  int lane = tid & 63, wid = tid >> 6;
  int wk = wid >> 2, wt = wid & 3;       // 2 waves along k, 4 along t
  int q = lane >> 4, mm = lane & 15;

  // A staging constants: thread covers granule gi = it*512+tid (it=0..1);
  // LDS linear pos gi holds source granule (gi&7)^(row&7) of the chunk.
  int stR[2], stC[2], stL[2];
#pragma unroll
  for (int it = 0; it < 2; it++) {
    int gi = it * 512 + tid;
    int r = gi >> 3, g = gi & 7;
    stR[it] = r;                         // 0..127
    stC[it] = (g ^ (r & 7)) << 3;        // u16 col offset within 64-col chunk
    stL[it] = gi << 3;                   // u16 linear LDS offset
  }

  // A-fragment read offsets (octet-permutation swizzle), per kk
  int foff[2];
#pragma unroll
  for (int kk = 0; kk < 2; kk++)
    foff[kk] = ((((kk << 2) | q) ^ (mm & 7)) << 3);

  // ---- prologue: c2 -> LDS; B hi/lo -> registers; stage A chunks 0..2 ----
  float2 c2v2 = *(const float2*)&c2[kbeg + tid * 2];
  bf16x8 fbh[2][8], fbl[2][8];
#pragma unroll
  for (int j = 0; j < 2; ++j)
#pragma unroll
    for (int sl = 0; sl < 8; ++sl) {
      const size_t gb = (size_t)(t0 + wt * 32 + j * 16 + mm) * CDIM + sl * 32 + q * 8;
      fbh[j][sl] = *(const bf16x8*)&eth[gb];
      fbl[j][sl] = *(const bf16x8*)&etl[gb];
    }
  *(float2*)&c2L[tid * 2] = c2v2;
#pragma unroll
  for (int p = 0; p < 3; ++p) {
#pragma unroll
    for (int it = 0; it < 2; ++it) {
      const size_t ga = (size_t)(kbeg + stR[it]) * CDIM + p * 64 + stC[it];
      gload16(&cbh[ga], &AhL[p][stL[it]]);
      gload16(&cbl[ga], &AlL[p][stL[it]]);
    }
  }
  asm volatile("s_waitcnt lgkmcnt(0)" ::: "memory");   // c2L ds_write done

  float rbv[2]; int rbi[2];
#pragma unroll
  for (int j = 0; j < 2; j++) { rbv[j] = INFINITY; rbi[j] = 0x7fffffff; }

  const floatx4 z4 = {0.f, 0.f, 0.f, 0.f};
  floatx4 acc[4][2];
#pragma unroll
  for (int i = 0; i < 4; i++)
#pragma unroll
    for (int j = 0; j < 2; j++) acc[i][j] = z4;

  for (int ks = 0; ks < 8; ++ks) {       // 8 k-steps of 128 rows
#pragma unroll
    for (int cc = 0; cc < 4; ++cc) {     // 4 chunks of BK=64; buf = cc
      // counted wait: my chunk-(ks*4+cc) granules (4 oldest) landed;
      // barrier: everyone's landed + everyone done reading buf (cc+3)&3.
      asm volatile("s_waitcnt vmcnt(8)" ::: "memory");
      __builtin_amdgcn_s_barrier();
      __builtin_amdgcn_sched_barrier(0);

      // prefetch chunk n+3 (wrapped; tail wraps are harmless re-reads)
      {
        int nn = (ks * 4 + cc + 3) & 31;
        int k0n = kbeg + ((nn >> 2) * 128);
        const int c0n = ((cc + 3) & 3) * 64;
        const int nb = (cc + 3) & 3;
#pragma unroll
        for (int it = 0; it < 2; ++it) {
          const size_t ga = (size_t)(k0n + stR[it]) * CDIM + c0n + stC[it];
          gload16(&cbh[ga], &AhL[nb][stL[it]]);
          gload16(&cbl[ga], &AlL[nb][stL[it]]);
        }
      }

      // MFMA cluster on buf cc: per 32-col slice (kk): hihi -> lohi -> hilo
      __builtin_amdgcn_s_setprio(1);
#pragma unroll
      for (int kk = 0; kk < 2; ++kk) {
        bf16x8 fah[4];
#pragma unroll
        for (int i = 0; i < 4; i++)
          fah[i] = *(const bf16x8*)&AhL[cc][(wk * 64 + i * 16 + mm) * 64 + foff[kk]];
#pragma unroll
        for (int i = 0; i < 4; i++)
#pragma unroll
          for (int j = 0; j < 2; j++)
            acc[i][j] = __builtin_amdgcn_mfma_f32_16x16x32_bf16(fah[i], fbh[j][cc * 2 + kk], acc[i][j], 0, 0, 0);
#pragma unroll
        for (int i = 0; i < 4; i++) {
          bf16x8 fl = *(const bf16x8*)&AlL[cc][(wk * 64 + i * 16 + mm) * 64 + foff[kk]];
#pragma unroll
          for (int j = 0; j < 2; j++)
            acc[i][j] = __builtin_amdgcn_mfma_f32_16x16x32_bf16(fl, fbh[j][cc * 2 + kk], acc[i][j], 0, 0, 0);
        }
#pragma unroll
        for (int j = 0; j < 2; j++) {
#pragma unroll
          for (int i = 0; i < 4; i++)
            acc[i][j] = __builtin_amdgcn_mfma_f32_16x16x32_bf16(fah[i], fbl[j][cc * 2 + kk], acc[i][j], 0, 0, 0);
        }
      }
      __builtin_amdgcn_s_setprio(0);
    }

    // k-step epilogue: fold acc into running argmin (c2 from LDS), reset acc
#pragma unroll
    for (int i = 0; i < 4; i++) {
      floatx4 cv = *(const floatx4*)&c2L[ks * 128 + wk * 64 + i * 16 + q * 4];
#pragma unroll
      for (int r4 = 0; r4 < 4; r4++) {
        int kg = kbeg + ks * 128 + wk * 64 + i * 16 + q * 4 + r4;
        float c2v = cv[r4];
#pragma unroll
        for (int j = 0; j < 2; j++) {
          float s = c2v - 2.0f * acc[i][j][r4];
          if (s < rbv[j]) { rbv[j] = s; rbi[j] = kg; }
        }
      }
    }
#pragma unroll
    for (int i = 0; i < 4; i++)
#pragma unroll
      for (int j = 0; j < 2; j++) acc[i][j] = z4;
  }

  // cross-lane reduce over q (lanes 16/32 apart hold same t)
#pragma unroll
  for (int j = 0; j < 2; j++) {
    float v = rbv[j]; int ii = rbi[j];
    float ov = __shfl_xor(v, 16, 64); int oi = __shfl_xor(ii, 16, 64);
    if (ov < v || (ov == v && oi < ii)) { v = ov; ii = oi; }
    ov = __shfl_xor(v, 32, 64); oi = __shfl_xor(ii, 32, 64);
    if (ov < v || (ov == v && oi < ii)) { v = ov; ii = oi; }
    rbv[j] = v; rbi[j] = ii;
  }
  if (q == 0) {
#pragma unroll
    for (int j = 0; j < 2; j++) {
      mv[wk][wt * 32 + j * 16 + mm] = rbv[j];
      mi[wk][wt * 32 + j * 16 + mm] = rbi[j];
    }
  }
  __syncthreads();   // full drain: dummy prefetch DMAs + mv/mi publication
  if (tid < 128) {
    float v0 = mv[0][tid]; int i0 = mi[0][tid];
    float v1 = mv[1][tid]; int i1 = mi[1][tid];
    if (v1 < v0 || (v1 == v0 && i1 < i0)) { v0 = v1; i0 = i1; }
    pv[(size_t)blockIdx.y * TDIM + t0 + tid] = v0;
    pi[(size_t)blockIdx.y * TDIM + t0 + tid] = i0;
  }
}

// ---------------------------------------------------------------------------
// merge k-splits; emit int idx (for gather) and float idx (output 1)
// ---------------------------------------------------------------------------
__global__ __launch_bounds__(256) void merge_argmin(
    const float* __restrict__ pv, const int* __restrict__ pi,
    int* __restrict__ idx, float* __restrict__ idxf) {
  int t = blockIdx.x * 256 + threadIdx.x;
  float bv = INFINITY; int bi = 0x7fffffff;
  for (int s = 0; s < KSPLIT; s++) {
    float v = pv[(size_t)s * TDIM + t];
    int ii = pi[(size_t)s * TDIM + t];
    if (v < bv || (v == bv && ii < bi)) { bv = v; bi = ii; }
  }
  idx[t] = bi;
  idxf[t] = (float)bi;
}

// ---------------------------------------------------------------------------
// gather: zqT[t][c] = split(cb[idx[t]][c]); 4 t per block, float4 loads.
// ---------------------------------------------------------------------------
__global__ __launch_bounds__(256) void gather_split(
    const int* __restrict__ idx, const float* __restrict__ cb,
    u16* __restrict__ zqh, u16* __restrict__ zql) {
  int t = blockIdx.x * 4 + (threadIdx.x >> 6);
  int c4 = (threadIdx.x & 63) * 4;
  int k = idx[t];
  float4 x = *(const float4*)&cb[(size_t)k * CDIM + c4];
  u16 h0 = f2bf(x.x), h1 = f2bf(x.y), h2 = f2bf(x.z), h3 = f2bf(x.w);
  u16 l0 = f2bf(x.x - bf2f(h0)), l1 = f2bf(x.y - bf2f(h1));
  u16 l2 = f2bf(x.z - bf2f(h2)), l3 = f2bf(x.w - bf2f(h3));
  ushort4 hv = {h0, h1, h2, h3}, lv = {l0, l1, l2, l3};
  *(ushort4*)&zqh[(size_t)t * CDIM + c4] = hv;
  *(ushort4*)&zql[(size_t)t * CDIM + c4] = lv;
}

extern "C" void kernel_launch(void* const* d_in, const int* in_sizes, int n_in,
                              void* d_out, int out_size, void* d_ws, size_t ws_size,
                              hipStream_t stream) {
  const float* z     = (const float*)d_in[0];
  const float* in_v  = (const float*)d_in[1];
  const float* in_g  = (const float*)d_in[2];
  const float* in_b  = (const float*)d_in[3];
  const float* out_v = (const float*)d_in[4];
  const float* out_g = (const float*)d_in[5];
  const float* out_b = (const float*)d_in[6];
  const float* cb    = (const float*)d_in[7];

  float* ws    = (float*)d_ws;
  u16*   winh  = (u16*)(ws + OFF_WINH);
  u16*   winl  = (u16*)(ws + OFF_WINL);
  u16*   wouth = (u16*)(ws + OFF_WOUTH);
  u16*   woutl = (u16*)(ws + OFF_WOUTL);
  u16*   cbh   = (u16*)(ws + OFF_CBH);
  u16*   cbl   = (u16*)(ws + OFF_CBL);
  float* c2    = ws + OFF_C2;
  u16*   zth   = (u16*)(ws + OFF_ZTH);
  u16*   ztl   = (u16*)(ws + OFF_ZTL);
  float* z_e   = ws + OFF_ZE;
  float* pv    = ws + OFF_PV;
  int*   pi    = (int*)(ws + OFF_PI);
  int*   idxw  = (int*)(ws + OFF_IDX);
  u16*   eth   = (u16*)(ws + OFF_ETH);   // aliases zth (dead after in_proj)
  u16*   etl   = (u16*)(ws + OFF_ETL);
  u16*   zqh   = eth;                    // aliases eth (dead after dist)
  u16*   zql   = etl;

  float* outp = (float*)d_out;                 // (1024 x 16384) fp32
  float* idxf = outp + (size_t)DDIM * TDIM;    // indices as float32

  // weight prep: all weights emitted directly as split-bf16
  rownorm_split<<<CDIM, 256, 0, stream>>>(in_v, in_g, winh, winl, nullptr, DDIM, 0);
  rownorm_split<<<DDIM, 256, 0, stream>>>(out_v, out_g, wouth, woutl, nullptr, CDIM, 0);
  rownorm_split<<<KDIM, 256, 0, stream>>>(cb, nullptr, cbh, cbl, c2, CDIM, 1);

  // z -> zT split (for in_proj B operand)
  transpose_split_z<<<dim3(TDIM / 64, DDIM / 64), 256, 0, stream>>>(z, zth, ztl);

  // z_e = W_in @ z + in_b  (split-bf16 MFMA, BN=64, K=1024)
  gemm_mfma_in<<<dim3(TDIM / 64, CDIM / 128), 256, 0, stream>>>(
      winh, winl, zth, ztl, in_b, z_e, DDIM);

  // fused colnorm + transpose + split -> eth/etl [t][c]
  finish_ze<<<TDIM / 32, 256, 0, stream>>>(z_e, eth, etl);

  // nearest-codebook argmin (k-split x8): B-in-regs + counted-vmcnt A pipe
  dist_mfma<<<dim3(TDIM / 128, KSPLIT), 512, 0, stream>>>(eth, etl, cbh, cbl, c2, pv, pi);
  merge_argmin<<<TDIM / 256, 256, 0, stream>>>(pv, pi, idxw, idxf);

  // zq = cb[idx] -> split [t][c]
  gather_split<<<TDIM / 4, 256, 0, stream>>>(idxw, cb, zqh, zql);

  // out = W_out @ z_q + out_b  (split-bf16 MFMA, K=256)
  gemm_mfma_bias<<<dim3(TDIM / 128, DDIM / 128), 256, 0, stream>>>(
      wouth, woutl, zqh, zql, out_b, outp, CDIM);
}

// Round 5
// 423.454 us; speedup vs baseline: 1.3540x; 1.0219x over previous
//
#include <hip/hip_runtime.h>
#include <hip/hip_bf16.h>
#include <math.h>

#define TDIM 16384
#define DDIM 1024
#define CDIM 256
#define KDIM 8192
#define KSPLIT 8

typedef unsigned short u16;
typedef __attribute__((ext_vector_type(8))) short bf16x8;
typedef __attribute__((ext_vector_type(8))) unsigned short us8;
typedef __attribute__((ext_vector_type(4))) float floatx4;

// ---- workspace layout (float offsets) ----
static const size_t OFF_WINH  = 0;                                     // 256x1024 u16
static const size_t OFF_WINL  = OFF_WINH  + (size_t)CDIM * DDIM / 2;
static const size_t OFF_WOUTH = OFF_WINL  + (size_t)CDIM * DDIM / 2;   // 1024x256 u16
static const size_t OFF_WOUTL = OFF_WOUTH + (size_t)DDIM * CDIM / 2;
static const size_t OFF_CBH   = OFF_WOUTL + (size_t)DDIM * CDIM / 2;   // 8192x256 u16
static const size_t OFF_CBL   = OFF_CBH   + (size_t)KDIM * CDIM / 2;
static const size_t OFF_C2    = OFF_CBL   + (size_t)KDIM * CDIM / 2;   // 8192 f32
static const size_t OFF_ZTH   = OFF_C2    + (size_t)KDIM;              // 16384x1024 u16 [t][d]
static const size_t OFF_ZTL   = OFF_ZTH   + (size_t)TDIM * DDIM / 2;
static const size_t OFF_ZE    = OFF_ZTL   + (size_t)TDIM * DDIM / 2;   // 256x16384 f32
static const size_t OFF_PV    = OFF_ZE    + (size_t)CDIM * TDIM;       // 8x16384 f32
static const size_t OFF_PI    = OFF_PV    + (size_t)KSPLIT * TDIM;     // 8x16384 i32
static const size_t OFF_IDX   = OFF_PI    + (size_t)KSPLIT * TDIM;     // 16384 i32
// eth/etl [t][c] alias ZTH (zth/ztl dead after in_proj gemm);
// zqh/zql alias the same region again (eth/etl dead after dist_mfma).
static const size_t OFF_ETH   = OFF_ZTH;
static const size_t OFF_ETL   = OFF_ZTH + (size_t)TDIM * CDIM / 2;

static __device__ __forceinline__ u16 f2bf(float x) {
  __hip_bfloat16 h = __float2bfloat16(x);
  return *(u16*)&h;
}
static __device__ __forceinline__ float bf2f(u16 u) {
  __hip_bfloat16 h; *(u16*)&h = u;
  return __bfloat162float(h);
}

// async global->LDS 16B copy (LDS dest = wave-uniform base + lane*16;
// our per-lane dests are consecutive-16B by construction).
static __device__ __forceinline__ void gload16(const u16* g, u16* l) {
  __builtin_amdgcn_global_load_lds(
      (__attribute__((address_space(1))) void*)g,
      (__attribute__((address_space(3))) void*)l, 16, 0, 0);
}

// ---------------------------------------------------------------------------
// Row-wise L2 normalize -> bf16 hi/lo split. Optional g, clip, c2.
// ---------------------------------------------------------------------------
__global__ __launch_bounds__(256) void rownorm_split(
    const float* __restrict__ v, const float* __restrict__ g,
    u16* __restrict__ hi, u16* __restrict__ lo, float* __restrict__ c2,
    int ncols, int clip) {
  __shared__ float red[256];
  int row = blockIdx.x;
  const float* vr = v + (size_t)row * ncols;
  float s = 0.f;
  for (int j = threadIdx.x; j < ncols; j += 256) { float x = vr[j]; s += x * x; }
  red[threadIdx.x] = s;
  __syncthreads();
  for (int off = 128; off > 0; off >>= 1) {
    if (threadIdx.x < off) red[threadIdx.x] += red[threadIdx.x + off];
    __syncthreads();
  }
  float norm = sqrtf(red[0]);
  if (clip) norm = fmaxf(norm, 1e-12f);
  float scale = (g ? g[row] : 1.0f) / norm;
  float s2 = 0.f;
  for (int j = threadIdx.x; j < ncols; j += 256) {
    float y = vr[j] * scale;
    u16 hh = f2bf(y);
    u16 ll = f2bf(y - bf2f(hh));
    hi[(size_t)row * ncols + j] = hh;
    lo[(size_t)row * ncols + j] = ll;
    s2 += y * y;
  }
  if (c2) {
    __syncthreads();
    red[threadIdx.x] = s2;
    __syncthreads();
    for (int off = 128; off > 0; off >>= 1) {
      if (threadIdx.x < off) red[threadIdx.x] += red[threadIdx.x + off];
      __syncthreads();
    }
    if (threadIdx.x == 0) c2[row] = red[0];
  }
}

// ---------------------------------------------------------------------------
// z [d][t] fp32 -> zth/ztl [t][d] bf16 hi/lo (LDS 64x64 tile transpose)
// ---------------------------------------------------------------------------
__global__ __launch_bounds__(256) void transpose_split_z(
    const float* __restrict__ z, u16* __restrict__ zth, u16* __restrict__ ztl) {
  __shared__ float tile[64][65];
  int t0 = blockIdx.x * 64, d0 = blockIdx.y * 64;
  int tl = threadIdx.x & 63, grp = threadIdx.x >> 6;
#pragma unroll
  for (int r = 0; r < 16; r++) {
    int d = grp * 16 + r;
    tile[d][tl] = z[(size_t)(d0 + d) * TDIM + t0 + tl];
  }
  __syncthreads();
#pragma unroll
  for (int r = 0; r < 16; r++) {
    int t = grp * 16 + r;
    float x = tile[tl][t];
    u16 h = f2bf(x);
    u16 l = f2bf(x - bf2f(h));
    zth[(size_t)(t0 + t) * DDIM + d0 + tl] = h;
    ztl[(size_t)(t0 + t) * DDIM + d0 + tl] = l;
  }
}

// ---------------------------------------------------------------------------
// in_proj split-bf16 MFMA GEMM, BN=64: C[m][t] = A[m]·B[t] + bias[m]
// ---------------------------------------------------------------------------
__global__ __launch_bounds__(256) void gemm_mfma_in(
    const u16* __restrict__ ah_g, const u16* __restrict__ al_g,
    const u16* __restrict__ bh_g, const u16* __restrict__ bl_g,
    const float* __restrict__ bias, float* __restrict__ C, int K) {
  __shared__ u16 Ah[128 * 32], Al[128 * 32];
  __shared__ u16 Bh[64 * 32],  Bl[64 * 32];
  int tid = threadIdx.x;
  int n0 = blockIdx.x * 64;      // t
  int m0 = blockIdx.y * 128;     // output rows
  int lane = tid & 63, wid = tid >> 6;
  int wr = wid >> 1, wc = wid & 1;
  int q = lane >> 4, mm = lane & 15;
  int h = tid & 1;
  int sr = ((tid >> 1) ^ (h << 2)) & 127;
  int ssw = (sr ^ (sr >> 2)) & 3;
  int o0 = sr * 32 + ((((h << 1))     ^ ssw) << 3);
  int o1 = sr * 32 + ((((h << 1) | 1) ^ ssw) << 3);
  int gcol = h * 16;
  // B staging (64 rows): threads tid<128 cover 64 rows x 2 halves
  int sb = ((tid >> 1) ^ (h << 2)) & 63;
  int ssb = (sb ^ (sb >> 2)) & 3;
  int p0 = sb * 32 + ((((h << 1))     ^ ssb) << 3);
  int p1 = sb * 32 + ((((h << 1) | 1) ^ ssb) << 3);
  int sm = (mm ^ (mm >> 2)) & 3;
  int cq = (q ^ sm) << 3;

  const floatx4 z4 = {0.f, 0.f, 0.f, 0.f};
  floatx4 acc[4][2];
#pragma unroll
  for (int i = 0; i < 4; i++)
#pragma unroll
    for (int j = 0; j < 2; j++) acc[i][j] = z4;

  for (int c0 = 0; c0 < K; c0 += 32) {
    const size_t ga = (size_t)(m0 + sr) * K + c0 + gcol;
    us8 a_h0 = *(const us8*)&ah_g[ga];
    us8 a_h1 = *(const us8*)&ah_g[ga + 8];
    us8 a_l0 = *(const us8*)&al_g[ga];
    us8 a_l1 = *(const us8*)&al_g[ga + 8];
    us8 b_h0, b_h1, b_l0, b_l1;
    if (tid < 128) {
      const size_t gb = (size_t)(n0 + sb) * K + c0 + gcol;
      b_h0 = *(const us8*)&bh_g[gb];
      b_h1 = *(const us8*)&bh_g[gb + 8];
      b_l0 = *(const us8*)&bl_g[gb];
      b_l1 = *(const us8*)&bl_g[gb + 8];
    }
    __syncthreads();
    *(us8*)&Ah[o0] = a_h0; *(us8*)&Ah[o1] = a_h1;
    *(us8*)&Al[o0] = a_l0; *(us8*)&Al[o1] = a_l1;
    if (tid < 128) {
      *(us8*)&Bh[p0] = b_h0; *(us8*)&Bh[p1] = b_h1;
      *(us8*)&Bl[p0] = b_l0; *(us8*)&Bl[p1] = b_l1;
    }
    __syncthreads();

    bf16x8 fa[4], fb[2];
#pragma unroll
    for (int i = 0; i < 4; i++)
      fa[i] = *(const bf16x8*)&Ah[(wr * 64 + i * 16 + mm) * 32 + cq];
#pragma unroll
    for (int j = 0; j < 2; j++)
      fb[j] = *(const bf16x8*)&Bh[(wc * 32 + j * 16 + mm) * 32 + cq];
#pragma unroll
    for (int i = 0; i < 4; i++)
#pragma unroll
      for (int j = 0; j < 2; j++)
        acc[i][j] = __builtin_amdgcn_mfma_f32_16x16x32_bf16(fa[i], fb[j], acc[i][j], 0, 0, 0);
#pragma unroll
    for (int i = 0; i < 4; i++) {
      bf16x8 fl = *(const bf16x8*)&Al[(wr * 64 + i * 16 + mm) * 32 + cq];
#pragma unroll
      for (int j = 0; j < 2; j++)
        acc[i][j] = __builtin_amdgcn_mfma_f32_16x16x32_bf16(fl, fb[j], acc[i][j], 0, 0, 0);
    }
#pragma unroll
    for (int j = 0; j < 2; j++) {
      bf16x8 fl = *(const bf16x8*)&Bl[(wc * 32 + j * 16 + mm) * 32 + cq];
#pragma unroll
      for (int i = 0; i < 4; i++)
        acc[i][j] = __builtin_amdgcn_mfma_f32_16x16x32_bf16(fa[i], fl, acc[i][j], 0, 0, 0);
    }
  }

#pragma unroll
  for (int i = 0; i < 4; i++) {
#pragma unroll
    for (int r = 0; r < 4; r++) {
      int m_loc = wr * 64 + i * 16 + q * 4 + r;
      float bb = bias[m0 + m_loc];
      float* crow = &C[(size_t)(m0 + m_loc) * TDIM + n0 + wc * 32 + mm];
#pragma unroll
      for (int j = 0; j < 2; j++) crow[j * 16] = acc[i][j][r] + bb;
    }
  }
}

// ---------------------------------------------------------------------------
// out_proj split-bf16 MFMA GEMM + bias, BN=128 (R6/R7-verified).
// ---------------------------------------------------------------------------
__global__ __launch_bounds__(256) void gemm_mfma_bias(
    const u16* __restrict__ ah_g, const u16* __restrict__ al_g,
    const u16* __restrict__ bh_g, const u16* __restrict__ bl_g,
    const float* __restrict__ bias, float* __restrict__ C, int K) {
  __shared__ u16 Ah[128 * 32], Al[128 * 32];
  __shared__ u16 Bh[128 * 32], Bl[128 * 32];
  int tid = threadIdx.x;
  int n0 = blockIdx.x * 128;
  int m0 = blockIdx.y * 128;
  int lane = tid & 63, wid = tid >> 6;
  int wr = wid >> 1, wc = wid & 1;
  int q = lane >> 4, mm = lane & 15;
  int h = tid & 1;
  int sr = ((tid >> 1) ^ (h << 2)) & 127;
  int ssw = (sr ^ (sr >> 2)) & 3;
  int o0 = sr * 32 + ((((h << 1))     ^ ssw) << 3);
  int o1 = sr * 32 + ((((h << 1) | 1) ^ ssw) << 3);
  int gcol = h * 16;
  int sm = (mm ^ (mm >> 2)) & 3;
  int cq = (q ^ sm) << 3;

  const floatx4 z4 = {0.f, 0.f, 0.f, 0.f};
  floatx4 acc[4][4];
#pragma unroll
  for (int i = 0; i < 4; i++)
#pragma unroll
    for (int j = 0; j < 4; j++) acc[i][j] = z4;

  for (int c0 = 0; c0 < K; c0 += 32) {
    const size_t ga = (size_t)(m0 + sr) * K + c0 + gcol;
    const size_t gb = (size_t)(n0 + sr) * K + c0 + gcol;
    us8 a_h0 = *(const us8*)&ah_g[ga];
    us8 a_h1 = *(const us8*)&ah_g[ga + 8];
    us8 a_l0 = *(const us8*)&al_g[ga];
    us8 a_l1 = *(const us8*)&al_g[ga + 8];
    us8 b_h0 = *(const us8*)&bh_g[gb];
    us8 b_h1 = *(const us8*)&bh_g[gb + 8];
    us8 b_l0 = *(const us8*)&bl_g[gb];
    us8 b_l1 = *(const us8*)&bl_g[gb + 8];
    __syncthreads();
    *(us8*)&Ah[o0] = a_h0; *(us8*)&Ah[o1] = a_h1;
    *(us8*)&Al[o0] = a_l0; *(us8*)&Al[o1] = a_l1;
    *(us8*)&Bh[o0] = b_h0; *(us8*)&Bh[o1] = b_h1;
    *(us8*)&Bl[o0] = b_l0; *(us8*)&Bl[o1] = b_l1;
    __syncthreads();

    bf16x8 fa[4], fb[4];
#pragma unroll
    for (int i = 0; i < 4; i++)
      fa[i] = *(const bf16x8*)&Ah[(wr * 64 + i * 16 + mm) * 32 + cq];
#pragma unroll
    for (int j = 0; j < 4; j++)
      fb[j] = *(const bf16x8*)&Bh[(wc * 64 + j * 16 + mm) * 32 + cq];
#pragma unroll
    for (int i = 0; i < 4; i++)
#pragma unroll
      for (int j = 0; j < 4; j++)
        acc[i][j] = __builtin_amdgcn_mfma_f32_16x16x32_bf16(fa[i], fb[j], acc[i][j], 0, 0, 0);
#pragma unroll
    for (int i = 0; i < 4; i++) {
      bf16x8 fl = *(const bf16x8*)&Al[(wr * 64 + i * 16 + mm) * 32 + cq];
#pragma unroll
      for (int j = 0; j < 4; j++)
        acc[i][j] = __builtin_amdgcn_mfma_f32_16x16x32_bf16(fl, fb[j], acc[i][j], 0, 0, 0);
    }
#pragma unroll
    for (int j = 0; j < 4; j++) {
      bf16x8 fl = *(const bf16x8*)&Bl[(wc * 64 + j * 16 + mm) * 32 + cq];
#pragma unroll
      for (int i = 0; i < 4; i++)
        acc[i][j] = __builtin_amdgcn_mfma_f32_16x16x32_bf16(fa[i], fl, acc[i][j], 0, 0, 0);
    }
  }

#pragma unroll
  for (int i = 0; i < 4; i++) {
#pragma unroll
    for (int r = 0; r < 4; r++) {
      int m_loc = wr * 64 + i * 16 + q * 4 + r;
      float bb = bias[m0 + m_loc];
      float* crow = &C[(size_t)(m0 + m_loc) * TDIM + n0 + wc * 64 + mm];
#pragma unroll
      for (int j = 0; j < 4; j++) crow[j * 16] = acc[i][j][r] + bb;
    }
  }
}

// ---------------------------------------------------------------------------
// finish_ze: fused column-norm + transpose + bf16 split, 32-t tiles.
// ---------------------------------------------------------------------------
__global__ __launch_bounds__(256) void finish_ze(
    const float* __restrict__ ze, u16* __restrict__ eth, u16* __restrict__ etl) {
  __shared__ float tile[256][33];
  __shared__ float red[8][32];
  __shared__ float invs[32];
  int t0 = blockIdx.x * 32;
  int tl = threadIdx.x & 31, grp = threadIdx.x >> 5;
  float s = 0.f;
  for (int c = grp * 32; c < grp * 32 + 32; c++) {
    float v = ze[(size_t)c * TDIM + t0 + tl];
    tile[c][tl] = v;
    s += v * v;
  }
  red[grp][tl] = s;
  __syncthreads();
  if (grp == 0) {
    float tot = 0.f;
#pragma unroll
    for (int gg = 0; gg < 8; gg++) tot += red[gg][tl];
    invs[tl] = 1.0f / fmaxf(sqrtf(tot), 1e-12f);
  }
  __syncthreads();
#pragma unroll
  for (int r = 0; r < 4; r++) {
    int t = grp * 4 + r;
    float iv = invs[t];
#pragma unroll
    for (int cc = 0; cc < 8; cc++) {
      int cd = cc * 32 + tl;
      float x = tile[cd][t] * iv;
      u16 hh = f2bf(x);
      u16 ll = f2bf(x - bf2f(hh));
      eth[(size_t)(t0 + t) * CDIM + cd] = hh;
      etl[(size_t)(t0 + t) * CDIM + cd] = ll;
    }
  }
}

// ---------------------------------------------------------------------------
// dist_mfma helpers (R12): macro-pipelined phases.
// Stage one 4-chunk macro (128 k-rows x 128 cols, hi+lo) via gload_lds.
// LDS dest linear in tid (gload_lds-compatible); source granule XOR'd
// g ^ ((r>>1)&3) so the octet-permutation read below is conflict-free.
// ---------------------------------------------------------------------------
static __device__ __forceinline__ void stage_phase(
    const u16* __restrict__ cbh, const u16* __restrict__ cbl,
    u16* AhB, u16* AlB, int krow, int c0, int scol, int ldso) {
#pragma unroll
  for (int u = 0; u < 4; ++u) {
    const size_t ga = (size_t)krow * CDIM + c0 + u * 32 + scol;
    gload16(&cbh[ga], &AhB[u * 4096 + ldso]);
    gload16(&cbl[ga], &AlB[u * 4096 + ldso]);
  }
}

// Compute one 4-chunk macro. SL0 = B-register slice base (0 or 4).
// Per chunk: 8 ds_read_b128 + 24 MFMA; no barriers inside -> waves drift,
// LDS pipe overlaps MFMA pipe across waves.
// FMA order per 32-col slice: hihi -> lohi -> hilo (i outer / j inner for
// hihi+lohi; j outer / i inner for hilo) — IDENTICAL to R11 (bit-equal).
template <int SL0>
static __device__ __forceinline__ void dist_phase(
    const u16* AhB, const u16* AlB,
    const bf16x8 (&fbh)[2][8], const bf16x8 (&fbl)[2][8],
    floatx4 (&acc)[4][2], int arow, int foffA) {
#pragma unroll
  for (int u = 0; u < 4; ++u) {
    const u16* AhC = AhB + u * 4096;
    const u16* AlC = AlB + u * 4096;
    bf16x8 fah[4], fal[4];
#pragma unroll
    for (int i = 0; i < 4; i++)
      fah[i] = *(const bf16x8*)&AhC[(arow + i * 16) * 32 + foffA];
#pragma unroll
    for (int i = 0; i < 4; i++)
      fal[i] = *(const bf16x8*)&AlC[(arow + i * 16) * 32 + foffA];
    __builtin_amdgcn_s_setprio(1);
#pragma unroll
    for (int i = 0; i < 4; i++)
#pragma unroll
      for (int j = 0; j < 2; j++)
        acc[i][j] = __builtin_amdgcn_mfma_f32_16x16x32_bf16(fah[i], fbh[j][SL0 + u], acc[i][j], 0, 0, 0);
#pragma unroll
    for (int i = 0; i < 4; i++)
#pragma unroll
      for (int j = 0; j < 2; j++)
        acc[i][j] = __builtin_amdgcn_mfma_f32_16x16x32_bf16(fal[i], fbh[j][SL0 + u], acc[i][j], 0, 0, 0);
#pragma unroll
    for (int j = 0; j < 2; j++)
#pragma unroll
      for (int i = 0; i < 4; i++)
        acc[i][j] = __builtin_amdgcn_mfma_f32_16x16x32_bf16(fah[i], fbl[j][SL0 + u], acc[i][j], 0, 0, 0);
    __builtin_amdgcn_s_setprio(0);
  }
}

// ---------------------------------------------------------------------------
// dist + argmin via split-bf16 MFMA — R12 macro-pipeline:
//   - B (enc) hi+lo persistent in registers (128 VGPR/wave) — R11-verified.
//   - A (codebook): 2-deep macro double-buffer; macro = 4 x BK32 chunks =
//     64KB (hi+lo). ONE __syncthreads per macro (~3700cy compute window) vs
//     R11's per-930cy barrier: the drain-barrier is the arrival guarantee
//     for the macro staged a full window earlier, and within the window the
//     8 waves drift so ds_read and MFMA pipes overlap (R11 post-mortem:
//     measured = pipe SUM 484Kcy/CU; target = pipe MAX 246Kcy/CU).
//   - Stage m+1 issued right after the barrier (buffer it overwrites was
//     proven free by that same barrier).
// Per-(t,k) FMA sequence identical to R11 -> dist/indices bit-equal.
// LDS 133KB -> 1 block/CU, 8 waves (2/SIMD).
// ---------------------------------------------------------------------------
__global__ __launch_bounds__(512, 2) void dist_mfma(
    const u16* __restrict__ eth, const u16* __restrict__ etl,
    const u16* __restrict__ cbh, const u16* __restrict__ cbl,
    const float* __restrict__ c2, float* __restrict__ pv, int* __restrict__ pi) {
  __shared__ u16 Ah0[4 * 4096], Ah1[4 * 4096];   // 64 KB codebook-hi dbuf
  __shared__ u16 Al0[4 * 4096], Al1[4 * 4096];   // 64 KB codebook-lo dbuf
  __shared__ float c2L[1024];                    // 4 KB block k-range c2
  __shared__ float mv[2][128];
  __shared__ int   mi[2][128];

  int tid = threadIdx.x;
  int t0 = blockIdx.x * 128;
  int kbeg = blockIdx.y * (KDIM / KSPLIT);
  int lane = tid & 63, wid = tid >> 6;
  int wk = wid >> 2, wt = wid & 3;       // 2 waves along k, 4 along t
  int q = lane >> 4, mm = lane & 15;

  // staging constants: thread covers granule tid of each 8KB half-chunk
  int r = tid >> 2, g = tid & 3;
  int scol = (g ^ ((r >> 1) & 3)) << 3;  // XOR'd source col (u16)
  int ldso = tid * 8;                    // linear LDS offset (u16)
  // fragment-read constants (octet-permutation, conflict-free)
  int arow = wk * 64 + mm;
  int foffA = (q ^ ((mm >> 1) & 3)) << 3;

  // ---- prologue: c2 -> LDS; B hi/lo -> registers; stage macro 0 ----
  float2 c2v2 = *(const float2*)&c2[kbeg + tid * 2];
  bf16x8 fbh[2][8], fbl[2][8];
#pragma unroll
  for (int j = 0; j < 2; ++j)
#pragma unroll
    for (int sl = 0; sl < 8; ++sl) {
      const size_t gb = (size_t)(t0 + wt * 32 + j * 16 + mm) * CDIM + sl * 32 + q * 8;
      fbh[j][sl] = *(const bf16x8*)&eth[gb];
      fbl[j][sl] = *(const bf16x8*)&etl[gb];
    }
  *(float2*)&c2L[tid * 2] = c2v2;
  stage_phase(cbh, cbl, Ah0, Al0, kbeg + r, 0, scol, ldso);

  float rbv[2]; int rbi[2];
#pragma unroll
  for (int j = 0; j < 2; j++) { rbv[j] = INFINITY; rbi[j] = 0x7fffffff; }

  const floatx4 z4 = {0.f, 0.f, 0.f, 0.f};
  floatx4 acc[4][2];
#pragma unroll
  for (int i = 0; i < 4; i++)
#pragma unroll
    for (int j = 0; j < 2; j++) acc[i][j] = z4;

  for (int ks = 0; ks < 8; ++ks) {       // 8 k-steps of 128 rows
    // ---- phase A: cols 0-127 from buf0 ----
    __syncthreads();                     // macro 2ks landed; buf1 free
    stage_phase(cbh, cbl, Ah1, Al1, kbeg + ks * 128 + r, 128, scol, ldso);
    dist_phase<0>(Ah0, Al0, fbh, fbl, acc, arow, foffA);

    // ---- phase B: cols 128-255 from buf1 ----
    __syncthreads();                     // macro 2ks+1 landed; buf0 free
    if (ks < 7)
      stage_phase(cbh, cbl, Ah0, Al0, kbeg + (ks + 1) * 128 + r, 0, scol, ldso);
    dist_phase<4>(Ah1, Al1, fbh, fbl, acc, arow, foffA);

    // k-step epilogue: fold acc into running argmin (c2 from LDS), reset acc
#pragma unroll
    for (int i = 0; i < 4; i++) {
      floatx4 cv = *(const floatx4*)&c2L[ks * 128 + wk * 64 + i * 16 + q * 4];
#pragma unroll
      for (int r4 = 0; r4 < 4; r4++) {
        int kg = kbeg + ks * 128 + wk * 64 + i * 16 + q * 4 + r4;
        float c2v = cv[r4];
#pragma unroll
        for (int j = 0; j < 2; j++) {
          float s = c2v - 2.0f * acc[i][j][r4];
          if (s < rbv[j]) { rbv[j] = s; rbi[j] = kg; }
        }
      }
    }
#pragma unroll
    for (int i = 0; i < 4; i++)
#pragma unroll
      for (int j = 0; j < 2; j++) acc[i][j] = z4;
  }

  // cross-lane reduce over q (lanes 16/32 apart hold same t)
#pragma unroll
  for (int j = 0; j < 2; j++) {
    float v = rbv[j]; int ii = rbi[j];
    float ov = __shfl_xor(v, 16, 64); int oi = __shfl_xor(ii, 16, 64);
    if (ov < v || (ov == v && oi < ii)) { v = ov; ii = oi; }
    ov = __shfl_xor(v, 32, 64); oi = __shfl_xor(ii, 32, 64);
    if (ov < v || (ov == v && oi < ii)) { v = ov; ii = oi; }
    rbv[j] = v; rbi[j] = ii;
  }
  if (q == 0) {
#pragma unroll
    for (int j = 0; j < 2; j++) {
      mv[wk][wt * 32 + j * 16 + mm] = rbv[j];
      mi[wk][wt * 32 + j * 16 + mm] = rbi[j];
    }
  }
  __syncthreads();
  if (tid < 128) {
    float v0 = mv[0][tid]; int i0 = mi[0][tid];
    float v1 = mv[1][tid]; int i1 = mi[1][tid];
    if (v1 < v0 || (v1 == v0 && i1 < i0)) { v0 = v1; i0 = i1; }
    pv[(size_t)blockIdx.y * TDIM + t0 + tid] = v0;
    pi[(size_t)blockIdx.y * TDIM + t0 + tid] = i0;
  }
}

// ---------------------------------------------------------------------------
// merge k-splits; emit int idx (for gather) and float idx (output 1)
// ---------------------------------------------------------------------------
__global__ __launch_bounds__(256) void merge_argmin(
    const float* __restrict__ pv, const int* __restrict__ pi,
    int* __restrict__ idx, float* __restrict__ idxf) {
  int t = blockIdx.x * 256 + threadIdx.x;
  float bv = INFINITY; int bi = 0x7fffffff;
  for (int s = 0; s < KSPLIT; s++) {
    float v = pv[(size_t)s * TDIM + t];
    int ii = pi[(size_t)s * TDIM + t];
    if (v < bv || (v == bv && ii < bi)) { bv = v; bi = ii; }
  }
  idx[t] = bi;
  idxf[t] = (float)bi;
}

// ---------------------------------------------------------------------------
// gather: zqT[t][c] = split(cb[idx[t]][c]); 4 t per block, float4 loads.
// ---------------------------------------------------------------------------
__global__ __launch_bounds__(256) void gather_split(
    const int* __restrict__ idx, const float* __restrict__ cb,
    u16* __restrict__ zqh, u16* __restrict__ zql) {
  int t = blockIdx.x * 4 + (threadIdx.x >> 6);
  int c4 = (threadIdx.x & 63) * 4;
  int k = idx[t];
  float4 x = *(const float4*)&cb[(size_t)k * CDIM + c4];
  u16 h0 = f2bf(x.x), h1 = f2bf(x.y), h2 = f2bf(x.z), h3 = f2bf(x.w);
  u16 l0 = f2bf(x.x - bf2f(h0)), l1 = f2bf(x.y - bf2f(h1));
  u16 l2 = f2bf(x.z - bf2f(h2)), l3 = f2bf(x.w - bf2f(h3));
  ushort4 hv = {h0, h1, h2, h3}, lv = {l0, l1, l2, l3};
  *(ushort4*)&zqh[(size_t)t * CDIM + c4] = hv;
  *(ushort4*)&zql[(size_t)t * CDIM + c4] = lv;
}

extern "C" void kernel_launch(void* const* d_in, const int* in_sizes, int n_in,
                              void* d_out, int out_size, void* d_ws, size_t ws_size,
                              hipStream_t stream) {
  const float* z     = (const float*)d_in[0];
  const float* in_v  = (const float*)d_in[1];
  const float* in_g  = (const float*)d_in[2];
  const float* in_b  = (const float*)d_in[3];
  const float* out_v = (const float*)d_in[4];
  const float* out_g = (const float*)d_in[5];
  const float* out_b = (const float*)d_in[6];
  const float* cb    = (const float*)d_in[7];

  float* ws    = (float*)d_ws;
  u16*   winh  = (u16*)(ws + OFF_WINH);
  u16*   winl  = (u16*)(ws + OFF_WINL);
  u16*   wouth = (u16*)(ws + OFF_WOUTH);
  u16*   woutl = (u16*)(ws + OFF_WOUTL);
  u16*   cbh   = (u16*)(ws + OFF_CBH);
  u16*   cbl   = (u16*)(ws + OFF_CBL);
  float* c2    = ws + OFF_C2;
  u16*   zth   = (u16*)(ws + OFF_ZTH);
  u16*   ztl   = (u16*)(ws + OFF_ZTL);
  float* z_e   = ws + OFF_ZE;
  float* pv    = ws + OFF_PV;
  int*   pi    = (int*)(ws + OFF_PI);
  int*   idxw  = (int*)(ws + OFF_IDX);
  u16*   eth   = (u16*)(ws + OFF_ETH);   // aliases zth (dead after in_proj)
  u16*   etl   = (u16*)(ws + OFF_ETL);
  u16*   zqh   = eth;                    // aliases eth (dead after dist)
  u16*   zql   = etl;

  float* outp = (float*)d_out;                 // (1024 x 16384) fp32
  float* idxf = outp + (size_t)DDIM * TDIM;    // indices as float32

  // weight prep: all weights emitted directly as split-bf16
  rownorm_split<<<CDIM, 256, 0, stream>>>(in_v, in_g, winh, winl, nullptr, DDIM, 0);
  rownorm_split<<<DDIM, 256, 0, stream>>>(out_v, out_g, wouth, woutl, nullptr, CDIM, 0);
  rownorm_split<<<KDIM, 256, 0, stream>>>(cb, nullptr, cbh, cbl, c2, CDIM, 1);

  // z -> zT split (for in_proj B operand)
  transpose_split_z<<<dim3(TDIM / 64, DDIM / 64), 256, 0, stream>>>(z, zth, ztl);

  // z_e = W_in @ z + in_b  (split-bf16 MFMA, BN=64, K=1024)
  gemm_mfma_in<<<dim3(TDIM / 64, CDIM / 128), 256, 0, stream>>>(
      winh, winl, zth, ztl, in_b, z_e, DDIM);

  // fused colnorm + transpose + split -> eth/etl [t][c]
  finish_ze<<<TDIM / 32, 256, 0, stream>>>(z_e, eth, etl);

  // nearest-codebook argmin (k-split x8): B-in-regs + macro-pipelined A
  dist_mfma<<<dim3(TDIM / 128, KSPLIT), 512, 0, stream>>>(eth, etl, cbh, cbl, c2, pv, pi);
  merge_argmin<<<TDIM / 256, 256, 0, stream>>>(pv, pi, idxw, idxf);

  // zq = cb[idx] -> split [t][c]
  gather_split<<<TDIM / 4, 256, 0, stream>>>(idxw, cb, zqh, zql);

  // out = W_out @ z_q + out_b  (split-bf16 MFMA, K=256)
  gemm_mfma_bias<<<dim3(TDIM / 128, DDIM / 128), 256, 0, stream>>>(
      wouth, woutl, zqh, zql, out_b, outp, CDIM);
}

// Round 6
// 418.567 us; speedup vs baseline: 1.3698x; 1.0117x over previous
//
#include <hip/hip_runtime.h>
#include <hip/hip_bf16.h>
#include <math.h>

#define TDIM 16384
#define DDIM 1024
#define CDIM 256
#define KDIM 8192
#define KSPLIT 8

typedef unsigned short u16;
typedef __attribute__((ext_vector_type(8))) short bf16x8;
typedef __attribute__((ext_vector_type(8))) unsigned short us8;
typedef __attribute__((ext_vector_type(4))) float floatx4;

// ---- workspace layout (float offsets) ----
static const size_t OFF_WINH  = 0;                                     // 256x1024 u16
static const size_t OFF_WINL  = OFF_WINH  + (size_t)CDIM * DDIM / 2;
static const size_t OFF_WOUTH = OFF_WINL  + (size_t)CDIM * DDIM / 2;   // 1024x256 u16
static const size_t OFF_WOUTL = OFF_WOUTH + (size_t)DDIM * CDIM / 2;
static const size_t OFF_CBH   = OFF_WOUTL + (size_t)DDIM * CDIM / 2;   // 8192x256 u16
static const size_t OFF_CBL   = OFF_CBH   + (size_t)KDIM * CDIM / 2;
static const size_t OFF_C2    = OFF_CBL   + (size_t)KDIM * CDIM / 2;   // 8192 f32
static const size_t OFF_ZTH   = OFF_C2    + (size_t)KDIM;              // 16384x1024 u16 [t][d]
static const size_t OFF_ZTL   = OFF_ZTH   + (size_t)TDIM * DDIM / 2;
static const size_t OFF_ZE    = OFF_ZTL   + (size_t)TDIM * DDIM / 2;   // 256x16384 f32
static const size_t OFF_PV    = OFF_ZE    + (size_t)CDIM * TDIM;       // 8x16384 f32
static const size_t OFF_PI    = OFF_PV    + (size_t)KSPLIT * TDIM;     // 8x16384 i32
static const size_t OFF_IDX   = OFF_PI    + (size_t)KSPLIT * TDIM;     // 16384 i32
// eth/etl [t][c] alias ZTH (zth/ztl dead after in_proj gemm);
// zqh/zql alias the same region again (eth/etl dead after dist_mfma).
static const size_t OFF_ETH   = OFF_ZTH;
static const size_t OFF_ETL   = OFF_ZTH + (size_t)TDIM * CDIM / 2;

static __device__ __forceinline__ u16 f2bf(float x) {
  __hip_bfloat16 h = __float2bfloat16(x);
  return *(u16*)&h;
}
static __device__ __forceinline__ float bf2f(u16 u) {
  __hip_bfloat16 h; *(u16*)&h = u;
  return __bfloat162float(h);
}

// async global->LDS 16B copy (LDS dest = wave-uniform base + lane*16;
// our per-lane dests are consecutive-16B by construction).
static __device__ __forceinline__ void gload16(const u16* g, u16* l) {
  __builtin_amdgcn_global_load_lds(
      (__attribute__((address_space(1))) void*)g,
      (__attribute__((address_space(3))) void*)l, 16, 0, 0);
}

// ---------------------------------------------------------------------------
// Row-wise L2 normalize -> bf16 hi/lo split. Optional g, clip, c2.
// ---------------------------------------------------------------------------
__global__ __launch_bounds__(256) void rownorm_split(
    const float* __restrict__ v, const float* __restrict__ g,
    u16* __restrict__ hi, u16* __restrict__ lo, float* __restrict__ c2,
    int ncols, int clip) {
  __shared__ float red[256];
  int row = blockIdx.x;
  const float* vr = v + (size_t)row * ncols;
  float s = 0.f;
  for (int j = threadIdx.x; j < ncols; j += 256) { float x = vr[j]; s += x * x; }
  red[threadIdx.x] = s;
  __syncthreads();
  for (int off = 128; off > 0; off >>= 1) {
    if (threadIdx.x < off) red[threadIdx.x] += red[threadIdx.x + off];
    __syncthreads();
  }
  float norm = sqrtf(red[0]);
  if (clip) norm = fmaxf(norm, 1e-12f);
  float scale = (g ? g[row] : 1.0f) / norm;
  float s2 = 0.f;
  for (int j = threadIdx.x; j < ncols; j += 256) {
    float y = vr[j] * scale;
    u16 hh = f2bf(y);
    u16 ll = f2bf(y - bf2f(hh));
    hi[(size_t)row * ncols + j] = hh;
    lo[(size_t)row * ncols + j] = ll;
    s2 += y * y;
  }
  if (c2) {
    __syncthreads();
    red[threadIdx.x] = s2;
    __syncthreads();
    for (int off = 128; off > 0; off >>= 1) {
      if (threadIdx.x < off) red[threadIdx.x] += red[threadIdx.x + off];
      __syncthreads();
    }
    if (threadIdx.x == 0) c2[row] = red[0];
  }
}

// ---------------------------------------------------------------------------
// z [d][t] fp32 -> zth/ztl [t][d] bf16 hi/lo (LDS 64x64 tile transpose)
// ---------------------------------------------------------------------------
__global__ __launch_bounds__(256) void transpose_split_z(
    const float* __restrict__ z, u16* __restrict__ zth, u16* __restrict__ ztl) {
  __shared__ float tile[64][65];
  int t0 = blockIdx.x * 64, d0 = blockIdx.y * 64;
  int tl = threadIdx.x & 63, grp = threadIdx.x >> 6;
#pragma unroll
  for (int r = 0; r < 16; r++) {
    int d = grp * 16 + r;
    tile[d][tl] = z[(size_t)(d0 + d) * TDIM + t0 + tl];
  }
  __syncthreads();
#pragma unroll
  for (int r = 0; r < 16; r++) {
    int t = grp * 16 + r;
    float x = tile[tl][t];
    u16 h = f2bf(x);
    u16 l = f2bf(x - bf2f(h));
    zth[(size_t)(t0 + t) * DDIM + d0 + tl] = h;
    ztl[(size_t)(t0 + t) * DDIM + d0 + tl] = l;
  }
}

// ---------------------------------------------------------------------------
// in_proj split-bf16 MFMA GEMM, BN=64: C[m][t] = A[m]·B[t] + bias[m]
// ---------------------------------------------------------------------------
__global__ __launch_bounds__(256) void gemm_mfma_in(
    const u16* __restrict__ ah_g, const u16* __restrict__ al_g,
    const u16* __restrict__ bh_g, const u16* __restrict__ bl_g,
    const float* __restrict__ bias, float* __restrict__ C, int K) {
  __shared__ u16 Ah[128 * 32], Al[128 * 32];
  __shared__ u16 Bh[64 * 32],  Bl[64 * 32];
  int tid = threadIdx.x;
  int n0 = blockIdx.x * 64;      // t
  int m0 = blockIdx.y * 128;     // output rows
  int lane = tid & 63, wid = tid >> 6;
  int wr = wid >> 1, wc = wid & 1;
  int q = lane >> 4, mm = lane & 15;
  int h = tid & 1;
  int sr = ((tid >> 1) ^ (h << 2)) & 127;
  int ssw = (sr ^ (sr >> 2)) & 3;
  int o0 = sr * 32 + ((((h << 1))     ^ ssw) << 3);
  int o1 = sr * 32 + ((((h << 1) | 1) ^ ssw) << 3);
  int gcol = h * 16;
  // B staging (64 rows): threads tid<128 cover 64 rows x 2 halves
  int sb = ((tid >> 1) ^ (h << 2)) & 63;
  int ssb = (sb ^ (sb >> 2)) & 3;
  int p0 = sb * 32 + ((((h << 1))     ^ ssb) << 3);
  int p1 = sb * 32 + ((((h << 1) | 1) ^ ssb) << 3);
  int sm = (mm ^ (mm >> 2)) & 3;
  int cq = (q ^ sm) << 3;

  const floatx4 z4 = {0.f, 0.f, 0.f, 0.f};
  floatx4 acc[4][2];
#pragma unroll
  for (int i = 0; i < 4; i++)
#pragma unroll
    for (int j = 0; j < 2; j++) acc[i][j] = z4;

  for (int c0 = 0; c0 < K; c0 += 32) {
    const size_t ga = (size_t)(m0 + sr) * K + c0 + gcol;
    us8 a_h0 = *(const us8*)&ah_g[ga];
    us8 a_h1 = *(const us8*)&ah_g[ga + 8];
    us8 a_l0 = *(const us8*)&al_g[ga];
    us8 a_l1 = *(const us8*)&al_g[ga + 8];
    us8 b_h0, b_h1, b_l0, b_l1;
    if (tid < 128) {
      const size_t gb = (size_t)(n0 + sb) * K + c0 + gcol;
      b_h0 = *(const us8*)&bh_g[gb];
      b_h1 = *(const us8*)&bh_g[gb + 8];
      b_l0 = *(const us8*)&bl_g[gb];
      b_l1 = *(const us8*)&bl_g[gb + 8];
    }
    __syncthreads();
    *(us8*)&Ah[o0] = a_h0; *(us8*)&Ah[o1] = a_h1;
    *(us8*)&Al[o0] = a_l0; *(us8*)&Al[o1] = a_l1;
    if (tid < 128) {
      *(us8*)&Bh[p0] = b_h0; *(us8*)&Bh[p1] = b_h1;
      *(us8*)&Bl[p0] = b_l0; *(us8*)&Bl[p1] = b_l1;
    }
    __syncthreads();

    bf16x8 fa[4], fb[2];
#pragma unroll
    for (int i = 0; i < 4; i++)
      fa[i] = *(const bf16x8*)&Ah[(wr * 64 + i * 16 + mm) * 32 + cq];
#pragma unroll
    for (int j = 0; j < 2; j++)
      fb[j] = *(const bf16x8*)&Bh[(wc * 32 + j * 16 + mm) * 32 + cq];
#pragma unroll
    for (int i = 0; i < 4; i++)
#pragma unroll
      for (int j = 0; j < 2; j++)
        acc[i][j] = __builtin_amdgcn_mfma_f32_16x16x32_bf16(fa[i], fb[j], acc[i][j], 0, 0, 0);
#pragma unroll
    for (int i = 0; i < 4; i++) {
      bf16x8 fl = *(const bf16x8*)&Al[(wr * 64 + i * 16 + mm) * 32 + cq];
#pragma unroll
      for (int j = 0; j < 2; j++)
        acc[i][j] = __builtin_amdgcn_mfma_f32_16x16x32_bf16(fl, fb[j], acc[i][j], 0, 0, 0);
    }
#pragma unroll
    for (int j = 0; j < 2; j++) {
      bf16x8 fl = *(const bf16x8*)&Bl[(wc * 32 + j * 16 + mm) * 32 + cq];
#pragma unroll
      for (int i = 0; i < 4; i++)
        acc[i][j] = __builtin_amdgcn_mfma_f32_16x16x32_bf16(fa[i], fl, acc[i][j], 0, 0, 0);
    }
  }

#pragma unroll
  for (int i = 0; i < 4; i++) {
#pragma unroll
    for (int r = 0; r < 4; r++) {
      int m_loc = wr * 64 + i * 16 + q * 4 + r;
      float bb = bias[m0 + m_loc];
      float* crow = &C[(size_t)(m0 + m_loc) * TDIM + n0 + wc * 32 + mm];
#pragma unroll
      for (int j = 0; j < 2; j++) crow[j * 16] = acc[i][j][r] + bb;
    }
  }
}

// ---------------------------------------------------------------------------
// out_proj split-bf16 MFMA GEMM + bias, BN=128 (R6/R7-verified).
// ---------------------------------------------------------------------------
__global__ __launch_bounds__(256) void gemm_mfma_bias(
    const u16* __restrict__ ah_g, const u16* __restrict__ al_g,
    const u16* __restrict__ bh_g, const u16* __restrict__ bl_g,
    const float* __restrict__ bias, float* __restrict__ C, int K) {
  __shared__ u16 Ah[128 * 32], Al[128 * 32];
  __shared__ u16 Bh[128 * 32], Bl[128 * 32];
  int tid = threadIdx.x;
  int n0 = blockIdx.x * 128;
  int m0 = blockIdx.y * 128;
  int lane = tid & 63, wid = tid >> 6;
  int wr = wid >> 1, wc = wid & 1;
  int q = lane >> 4, mm = lane & 15;
  int h = tid & 1;
  int sr = ((tid >> 1) ^ (h << 2)) & 127;
  int ssw = (sr ^ (sr >> 2)) & 3;
  int o0 = sr * 32 + ((((h << 1))     ^ ssw) << 3);
  int o1 = sr * 32 + ((((h << 1) | 1) ^ ssw) << 3);
  int gcol = h * 16;
  int sm = (mm ^ (mm >> 2)) & 3;
  int cq = (q ^ sm) << 3;

  const floatx4 z4 = {0.f, 0.f, 0.f, 0.f};
  floatx4 acc[4][4];
#pragma unroll
  for (int i = 0; i < 4; i++)
#pragma unroll
    for (int j = 0; j < 4; j++) acc[i][j] = z4;

  for (int c0 = 0; c0 < K; c0 += 32) {
    const size_t ga = (size_t)(m0 + sr) * K + c0 + gcol;
    const size_t gb = (size_t)(n0 + sr) * K + c0 + gcol;
    us8 a_h0 = *(const us8*)&ah_g[ga];
    us8 a_h1 = *(const us8*)&ah_g[ga + 8];
    us8 a_l0 = *(const us8*)&al_g[ga];
    us8 a_l1 = *(const us8*)&al_g[ga + 8];
    us8 b_h0 = *(const us8*)&bh_g[gb];
    us8 b_h1 = *(const us8*)&bh_g[gb + 8];
    us8 b_l0 = *(const us8*)&bl_g[gb];
    us8 b_l1 = *(const us8*)&bl_g[gb + 8];
    __syncthreads();
    *(us8*)&Ah[o0] = a_h0; *(us8*)&Ah[o1] = a_h1;
    *(us8*)&Al[o0] = a_l0; *(us8*)&Al[o1] = a_l1;
    *(us8*)&Bh[o0] = b_h0; *(us8*)&Bh[o1] = b_h1;
    *(us8*)&Bl[o0] = b_l0; *(us8*)&Bl[o1] = b_l1;
    __syncthreads();

    bf16x8 fa[4], fb[4];
#pragma unroll
    for (int i = 0; i < 4; i++)
      fa[i] = *(const bf16x8*)&Ah[(wr * 64 + i * 16 + mm) * 32 + cq];
#pragma unroll
    for (int j = 0; j < 4; j++)
      fb[j] = *(const bf16x8*)&Bh[(wc * 64 + j * 16 + mm) * 32 + cq];
#pragma unroll
    for (int i = 0; i < 4; i++)
#pragma unroll
      for (int j = 0; j < 4; j++)
        acc[i][j] = __builtin_amdgcn_mfma_f32_16x16x32_bf16(fa[i], fb[j], acc[i][j], 0, 0, 0);
#pragma unroll
    for (int i = 0; i < 4; i++) {
      bf16x8 fl = *(const bf16x8*)&Al[(wr * 64 + i * 16 + mm) * 32 + cq];
#pragma unroll
      for (int j = 0; j < 4; j++)
        acc[i][j] = __builtin_amdgcn_mfma_f32_16x16x32_bf16(fl, fb[j], acc[i][j], 0, 0, 0);
    }
#pragma unroll
    for (int j = 0; j < 4; j++) {
      bf16x8 fl = *(const bf16x8*)&Bl[(wc * 64 + j * 16 + mm) * 32 + cq];
#pragma unroll
      for (int i = 0; i < 4; i++)
        acc[i][j] = __builtin_amdgcn_mfma_f32_16x16x32_bf16(fa[i], fl, acc[i][j], 0, 0, 0);
    }
  }

#pragma unroll
  for (int i = 0; i < 4; i++) {
#pragma unroll
    for (int r = 0; r < 4; r++) {
      int m_loc = wr * 64 + i * 16 + q * 4 + r;
      float bb = bias[m0 + m_loc];
      float* crow = &C[(size_t)(m0 + m_loc) * TDIM + n0 + wc * 64 + mm];
#pragma unroll
      for (int j = 0; j < 4; j++) crow[j * 16] = acc[i][j][r] + bb;
    }
  }
}

// ---------------------------------------------------------------------------
// finish_ze: fused column-norm + transpose + bf16 split, 32-t tiles.
// ---------------------------------------------------------------------------
__global__ __launch_bounds__(256) void finish_ze(
    const float* __restrict__ ze, u16* __restrict__ eth, u16* __restrict__ etl) {
  __shared__ float tile[256][33];
  __shared__ float red[8][32];
  __shared__ float invs[32];
  int t0 = blockIdx.x * 32;
  int tl = threadIdx.x & 31, grp = threadIdx.x >> 5;
  float s = 0.f;
  for (int c = grp * 32; c < grp * 32 + 32; c++) {
    float v = ze[(size_t)c * TDIM + t0 + tl];
    tile[c][tl] = v;
    s += v * v;
  }
  red[grp][tl] = s;
  __syncthreads();
  if (grp == 0) {
    float tot = 0.f;
#pragma unroll
    for (int gg = 0; gg < 8; gg++) tot += red[gg][tl];
    invs[tl] = 1.0f / fmaxf(sqrtf(tot), 1e-12f);
  }
  __syncthreads();
#pragma unroll
  for (int r = 0; r < 4; r++) {
    int t = grp * 4 + r;
    float iv = invs[t];
#pragma unroll
    for (int cc = 0; cc < 8; cc++) {
      int cd = cc * 32 + tl;
      float x = tile[cd][t] * iv;
      u16 hh = f2bf(x);
      u16 ll = f2bf(x - bf2f(hh));
      eth[(size_t)(t0 + t) * CDIM + cd] = hh;
      etl[(size_t)(t0 + t) * CDIM + cd] = ll;
    }
  }
}

// ---------------------------------------------------------------------------
// dist_mfma helpers (R13).
// stage_phase: one 4-chunk macro (128 k-rows x 128 cols, hi+lo) via gload_lds;
// linear LDS dest, source granule XOR g ^ ((r>>1)&3) (R12-verified, 0 confl).
// ---------------------------------------------------------------------------
static __device__ __forceinline__ void stage_phase(
    const u16* __restrict__ cbh, const u16* __restrict__ cbl,
    u16* AhB, u16* AlB, int krow, int c0, int scol, int ldso) {
#pragma unroll
  for (int u = 0; u < 4; ++u) {
    const size_t ga = (size_t)krow * CDIM + c0 + u * 32 + scol;
    gload16(&cbh[ga], &AhB[u * 4096 + ldso]);
    gload16(&cbl[ga], &AlB[u * 4096 + ldso]);
  }
}

// read one chunk's A fragments (hi+lo) from LDS
static __device__ __forceinline__ void lda_frags(
    const u16* AhC, const u16* AlC, int arow, int foffA,
    bf16x8 (&fh)[4], bf16x8 (&fl)[4]) {
#pragma unroll
  for (int i = 0; i < 4; i++)
    fh[i] = *(const bf16x8*)&AhC[(arow + i * 16) * 32 + foffA];
#pragma unroll
  for (int i = 0; i < 4; i++)
    fl[i] = *(const bf16x8*)&AlC[(arow + i * 16) * 32 + foffA];
}

// one chunk's MFMA cluster; FMA order = R12 (hihi i/j, lohi i/j, hilo j/i)
static __device__ __forceinline__ void mfma_chunk(
    const bf16x8 (&fah)[4], const bf16x8 (&fal)[4],
    bf16x8 bh0, bf16x8 bh1, bf16x8 bl0, bf16x8 bl1,
    floatx4 (&acc)[4][2]) {
  __builtin_amdgcn_s_setprio(1);
#pragma unroll
  for (int i = 0; i < 4; i++) {
    acc[i][0] = __builtin_amdgcn_mfma_f32_16x16x32_bf16(fah[i], bh0, acc[i][0], 0, 0, 0);
    acc[i][1] = __builtin_amdgcn_mfma_f32_16x16x32_bf16(fah[i], bh1, acc[i][1], 0, 0, 0);
  }
#pragma unroll
  for (int i = 0; i < 4; i++) {
    acc[i][0] = __builtin_amdgcn_mfma_f32_16x16x32_bf16(fal[i], bh0, acc[i][0], 0, 0, 0);
    acc[i][1] = __builtin_amdgcn_mfma_f32_16x16x32_bf16(fal[i], bh1, acc[i][1], 0, 0, 0);
  }
#pragma unroll
  for (int i = 0; i < 4; i++)
    acc[i][0] = __builtin_amdgcn_mfma_f32_16x16x32_bf16(fah[i], bl0, acc[i][0], 0, 0, 0);
#pragma unroll
  for (int i = 0; i < 4; i++)
    acc[i][1] = __builtin_amdgcn_mfma_f32_16x16x32_bf16(fah[i], bl1, acc[i][1], 0, 0, 0);
  __builtin_amdgcn_s_setprio(0);
}

// macro = 4 chunks, software-pipelined: prefetch chunk u+1's fragments
// BEFORE chunk u's MFMA cluster; setprio fences keep the issue order.
// MFMA(u) then waits (counted lgkmcnt, compiler-inserted) on reads issued
// one full cluster earlier -> LDS pipe hides under MFMA pipe.
template <int SL0>
static __device__ __forceinline__ void dist_phase_pl(
    const u16* AhB, const u16* AlB,
    const bf16x8 (&fbh)[2][8], const bf16x8 (&fbl)[2][8],
    floatx4 (&acc)[4][2], int arow, int foffA) {
  bf16x8 fahA[4], falA[4], fahB[4], falB[4];
  lda_frags(AhB, AlB, arow, foffA, fahA, falA);                        // chunk 0
  lda_frags(AhB + 4096, AlB + 4096, arow, foffA, fahB, falB);          // pre 1
  mfma_chunk(fahA, falA, fbh[0][SL0 + 0], fbh[1][SL0 + 0],
             fbl[0][SL0 + 0], fbl[1][SL0 + 0], acc);                   // c0
  lda_frags(AhB + 2 * 4096, AlB + 2 * 4096, arow, foffA, fahA, falA);  // pre 2
  mfma_chunk(fahB, falB, fbh[0][SL0 + 1], fbh[1][SL0 + 1],
             fbl[0][SL0 + 1], fbl[1][SL0 + 1], acc);                   // c1
  lda_frags(AhB + 3 * 4096, AlB + 3 * 4096, arow, foffA, fahB, falB);  // pre 3
  mfma_chunk(fahA, falA, fbh[0][SL0 + 2], fbh[1][SL0 + 2],
             fbl[0][SL0 + 2], fbl[1][SL0 + 2], acc);                   // c2
  mfma_chunk(fahB, falB, fbh[0][SL0 + 3], fbh[1][SL0 + 3],
             fbl[0][SL0 + 3], fbl[1][SL0 + 3], acc);                   // c3
}

// ---------------------------------------------------------------------------
// dist + argmin via split-bf16 MFMA — R13:
//   - B (enc) hi+lo in registers, PINNED via asm "+v" (R12 post-mortem:
//     VGPR_Count=116 < 128 proved the compiler rematerialized B loads
//     inside the loop -> hidden VMEM stalls in every MFMA cluster).
//   - Macro double-buffer (R12-verified) + in-macro fragment software
//     pipeline: prefetch chunk u+1 A-frags before chunk u MFMAs.
// Per-(t,k) FMA sequence identical to R12 -> dist/indices bit-equal.
// LDS 133KB -> 1 block/CU, 8 waves. VGPR target ~240 (cap 256 @ 2/SIMD).
// ---------------------------------------------------------------------------
__global__ __launch_bounds__(512, 2) void dist_mfma(
    const u16* __restrict__ eth, const u16* __restrict__ etl,
    const u16* __restrict__ cbh, const u16* __restrict__ cbl,
    const float* __restrict__ c2, float* __restrict__ pv, int* __restrict__ pi) {
  __shared__ u16 Ah0[4 * 4096], Ah1[4 * 4096];   // 64 KB codebook-hi dbuf
  __shared__ u16 Al0[4 * 4096], Al1[4 * 4096];   // 64 KB codebook-lo dbuf
  __shared__ float c2L[1024];                    // 4 KB block k-range c2
  __shared__ float mv[2][128];
  __shared__ int   mi[2][128];

  int tid = threadIdx.x;
  int t0 = blockIdx.x * 128;
  int kbeg = blockIdx.y * (KDIM / KSPLIT);
  int lane = tid & 63, wid = tid >> 6;
  int wk = wid >> 2, wt = wid & 3;       // 2 waves along k, 4 along t
  int q = lane >> 4, mm = lane & 15;

  // staging constants: thread covers granule tid of each 8KB half-chunk
  int r = tid >> 2, g = tid & 3;
  int scol = (g ^ ((r >> 1) & 3)) << 3;  // XOR'd source col (u16)
  int ldso = tid * 8;                    // linear LDS offset (u16)
  // fragment-read constants (octet-permutation, conflict-free)
  int arow = wk * 64 + mm;
  int foffA = (q ^ ((mm >> 1) & 3)) << 3;

  // ---- prologue: c2 -> LDS; B hi/lo -> registers (PINNED); stage macro 0 ----
  float2 c2v2 = *(const float2*)&c2[kbeg + tid * 2];
  bf16x8 fbh[2][8], fbl[2][8];
#pragma unroll
  for (int j = 0; j < 2; ++j)
#pragma unroll
    for (int sl = 0; sl < 8; ++sl) {
      const size_t gb = (size_t)(t0 + wt * 32 + j * 16 + mm) * CDIM + sl * 32 + q * 8;
      fbh[j][sl] = *(const bf16x8*)&eth[gb];
      fbl[j][sl] = *(const bf16x8*)&etl[gb];
    }
  // pin: value becomes asm-defined -> rematerialization impossible -> resident
#pragma unroll
  for (int j = 0; j < 2; ++j)
#pragma unroll
    for (int sl = 0; sl < 8; ++sl) {
      asm volatile("" : "+v"(fbh[j][sl]));
      asm volatile("" : "+v"(fbl[j][sl]));
    }
  *(float2*)&c2L[tid * 2] = c2v2;
  stage_phase(cbh, cbl, Ah0, Al0, kbeg + r, 0, scol, ldso);

  float rbv[2]; int rbi[2];
#pragma unroll
  for (int j = 0; j < 2; j++) { rbv[j] = INFINITY; rbi[j] = 0x7fffffff; }

  const floatx4 z4 = {0.f, 0.f, 0.f, 0.f};
  floatx4 acc[4][2];
#pragma unroll
  for (int i = 0; i < 4; i++)
#pragma unroll
    for (int j = 0; j < 2; j++) acc[i][j] = z4;

  for (int ks = 0; ks < 8; ++ks) {       // 8 k-steps of 128 rows
    // ---- phase A: cols 0-127 from buf0 ----
    __syncthreads();                     // macro 2ks landed; buf1 free
    stage_phase(cbh, cbl, Ah1, Al1, kbeg + ks * 128 + r, 128, scol, ldso);
    dist_phase_pl<0>(Ah0, Al0, fbh, fbl, acc, arow, foffA);

    // ---- phase B: cols 128-255 from buf1 ----
    __syncthreads();                     // macro 2ks+1 landed; buf0 free
    if (ks < 7)
      stage_phase(cbh, cbl, Ah0, Al0, kbeg + (ks + 1) * 128 + r, 0, scol, ldso);
    dist_phase_pl<4>(Ah1, Al1, fbh, fbl, acc, arow, foffA);

    // k-step epilogue: fold acc into running argmin (c2 from LDS), reset acc
#pragma unroll
    for (int i = 0; i < 4; i++) {
      floatx4 cv = *(const floatx4*)&c2L[ks * 128 + wk * 64 + i * 16 + q * 4];
#pragma unroll
      for (int r4 = 0; r4 < 4; r4++) {
        int kg = kbeg + ks * 128 + wk * 64 + i * 16 + q * 4 + r4;
        float c2v = cv[r4];
#pragma unroll
        for (int j = 0; j < 2; j++) {
          float s = c2v - 2.0f * acc[i][j][r4];
          if (s < rbv[j]) { rbv[j] = s; rbi[j] = kg; }
        }
      }
    }
#pragma unroll
    for (int i = 0; i < 4; i++)
#pragma unroll
      for (int j = 0; j < 2; j++) acc[i][j] = z4;
  }

  // cross-lane reduce over q (lanes 16/32 apart hold same t)
#pragma unroll
  for (int j = 0; j < 2; j++) {
    float v = rbv[j]; int ii = rbi[j];
    float ov = __shfl_xor(v, 16, 64); int oi = __shfl_xor(ii, 16, 64);
    if (ov < v || (ov == v && oi < ii)) { v = ov; ii = oi; }
    ov = __shfl_xor(v, 32, 64); oi = __shfl_xor(ii, 32, 64);
    if (ov < v || (ov == v && oi < ii)) { v = ov; ii = oi; }
    rbv[j] = v; rbi[j] = ii;
  }
  if (q == 0) {
#pragma unroll
    for (int j = 0; j < 2; j++) {
      mv[wk][wt * 32 + j * 16 + mm] = rbv[j];
      mi[wk][wt * 32 + j * 16 + mm] = rbi[j];
    }
  }
  __syncthreads();
  if (tid < 128) {
    float v0 = mv[0][tid]; int i0 = mi[0][tid];
    float v1 = mv[1][tid]; int i1 = mi[1][tid];
    if (v1 < v0 || (v1 == v0 && i1 < i0)) { v0 = v1; i0 = i1; }
    pv[(size_t)blockIdx.y * TDIM + t0 + tid] = v0;
    pi[(size_t)blockIdx.y * TDIM + t0 + tid] = i0;
  }
}

// ---------------------------------------------------------------------------
// merge k-splits; emit int idx (for gather) and float idx (output 1)
// ---------------------------------------------------------------------------
__global__ __launch_bounds__(256) void merge_argmin(
    const float* __restrict__ pv, const int* __restrict__ pi,
    int* __restrict__ idx, float* __restrict__ idxf) {
  int t = blockIdx.x * 256 + threadIdx.x;
  float bv = INFINITY; int bi = 0x7fffffff;
  for (int s = 0; s < KSPLIT; s++) {
    float v = pv[(size_t)s * TDIM + t];
    int ii = pi[(size_t)s * TDIM + t];
    if (v < bv || (v == bv && ii < bi)) { bv = v; bi = ii; }
  }
  idx[t] = bi;
  idxf[t] = (float)bi;
}

// ---------------------------------------------------------------------------
// gather: zqT[t][c] = split(cb[idx[t]][c]); 4 t per block, float4 loads.
// ---------------------------------------------------------------------------
__global__ __launch_bounds__(256) void gather_split(
    const int* __restrict__ idx, const float* __restrict__ cb,
    u16* __restrict__ zqh, u16* __restrict__ zql) {
  int t = blockIdx.x * 4 + (threadIdx.x >> 6);
  int c4 = (threadIdx.x & 63) * 4;
  int k = idx[t];
  float4 x = *(const float4*)&cb[(size_t)k * CDIM + c4];
  u16 h0 = f2bf(x.x), h1 = f2bf(x.y), h2 = f2bf(x.z), h3 = f2bf(x.w);
  u16 l0 = f2bf(x.x - bf2f(h0)), l1 = f2bf(x.y - bf2f(h1));
  u16 l2 = f2bf(x.z - bf2f(h2)), l3 = f2bf(x.w - bf2f(h3));
  ushort4 hv = {h0, h1, h2, h3}, lv = {l0, l1, l2, l3};
  *(ushort4*)&zqh[(size_t)t * CDIM + c4] = hv;
  *(ushort4*)&zql[(size_t)t * CDIM + c4] = lv;
}

extern "C" void kernel_launch(void* const* d_in, const int* in_sizes, int n_in,
                              void* d_out, int out_size, void* d_ws, size_t ws_size,
                              hipStream_t stream) {
  const float* z     = (const float*)d_in[0];
  const float* in_v  = (const float*)d_in[1];
  const float* in_g  = (const float*)d_in[2];
  const float* in_b  = (const float*)d_in[3];
  const float* out_v = (const float*)d_in[4];
  const float* out_g = (const float*)d_in[5];
  const float* out_b = (const float*)d_in[6];
  const float* cb    = (const float*)d_in[7];

  float* ws    = (float*)d_ws;
  u16*   winh  = (u16*)(ws + OFF_WINH);
  u16*   winl  = (u16*)(ws + OFF_WINL);
  u16*   wouth = (u16*)(ws + OFF_WOUTH);
  u16*   woutl = (u16*)(ws + OFF_WOUTL);
  u16*   cbh   = (u16*)(ws + OFF_CBH);
  u16*   cbl   = (u16*)(ws + OFF_CBL);
  float* c2    = ws + OFF_C2;
  u16*   zth   = (u16*)(ws + OFF_ZTH);
  u16*   ztl   = (u16*)(ws + OFF_ZTL);
  float* z_e   = ws + OFF_ZE;
  float* pv    = ws + OFF_PV;
  int*   pi    = (int*)(ws + OFF_PI);
  int*   idxw  = (int*)(ws + OFF_IDX);
  u16*   eth   = (u16*)(ws + OFF_ETH);   // aliases zth (dead after in_proj)
  u16*   etl   = (u16*)(ws + OFF_ETL);
  u16*   zqh   = eth;                    // aliases eth (dead after dist)
  u16*   zql   = etl;

  float* outp = (float*)d_out;                 // (1024 x 16384) fp32
  float* idxf = outp + (size_t)DDIM * TDIM;    // indices as float32

  // weight prep: all weights emitted directly as split-bf16
  rownorm_split<<<CDIM, 256, 0, stream>>>(in_v, in_g, winh, winl, nullptr, DDIM, 0);
  rownorm_split<<<DDIM, 256, 0, stream>>>(out_v, out_g, wouth, woutl, nullptr, CDIM, 0);
  rownorm_split<<<KDIM, 256, 0, stream>>>(cb, nullptr, cbh, cbl, c2, CDIM, 1);

  // z -> zT split (for in_proj B operand)
  transpose_split_z<<<dim3(TDIM / 64, DDIM / 64), 256, 0, stream>>>(z, zth, ztl);

  // z_e = W_in @ z + in_b  (split-bf16 MFMA, BN=64, K=1024)
  gemm_mfma_in<<<dim3(TDIM / 64, CDIM / 128), 256, 0, stream>>>(
      winh, winl, zth, ztl, in_b, z_e, DDIM);

  // fused colnorm + transpose + split -> eth/etl [t][c]
  finish_ze<<<TDIM / 32, 256, 0, stream>>>(z_e, eth, etl);

  // nearest-codebook argmin (k-split x8): pinned-B-regs + pipelined macro
  dist_mfma<<<dim3(TDIM / 128, KSPLIT), 512, 0, stream>>>(eth, etl, cbh, cbl, c2, pv, pi);
  merge_argmin<<<TDIM / 256, 256, 0, stream>>>(pv, pi, idxw, idxf);

  // zq = cb[idx] -> split [t][c]
  gather_split<<<TDIM / 4, 256, 0, stream>>>(idxw, cb, zqh, zql);

  // out = W_out @ z_q + out_b  (split-bf16 MFMA, K=256)
  gemm_mfma_bias<<<dim3(TDIM / 128, DDIM / 128), 256, 0, stream>>>(
      wouth, woutl, zqh, zql, out_b, outp, CDIM);
}